// Round 3
// baseline (650.358 us; speedup 1.0000x reference)
//
#include <hip/hip_runtime.h>
#include <hip/hip_bf16.h>
#include <math.h>

typedef unsigned short u16;
typedef __attribute__((ext_vector_type(8))) __bf16 bf16x8;
typedef __attribute__((ext_vector_type(4))) float f32x4;

__device__ __forceinline__ float bf2f(unsigned int u) {
    union { unsigned int i; float f; } x;
    x.i = (u & 0xffffu) << 16;
    return x.f;
}
__device__ __forceinline__ u16 f2bf(float f) {
    unsigned int i = __float_as_uint(f);
    unsigned int r = (i + 0x7fffu + ((i >> 16) & 1u)) >> 16;
    return (u16)r;
}

__device__ __forceinline__ void gload_lds16(const void* g, void* l) {
    __builtin_amdgcn_global_load_lds((const __attribute__((address_space(1))) void*)g,
                                     (__attribute__((address_space(3))) void*)l, 16, 0, 0);
}

// ---------------------------------------------------------------- dtype detect
// Reads first 64 dwords of Wq. If buffer is packed bf16 pairs, the LOW u16 of
// each dword is a bf16 VALUE from N(0,1/32): exponent field in [0x6e,0x7e]
// nearly always. If buffer is fp32, the low u16 is random mantissa bits:
// exponent-window hit rate ~6.6%. flag=1 -> fp32 inputs, flag=0 -> bf16.
__global__ void detect_dtype(const unsigned* __restrict__ wq, int* __restrict__ flag)
{
    int lane = threadIdx.x;   // 64 threads
    unsigned lo = wq[lane] & 0xffffu;
    unsigned e = (lo >> 7) & 0xffu;
    int m = (e >= 0x6e && e <= 0x7e) ? 1 : 0;
#pragma unroll
    for (int s = 1; s < 64; s <<= 1) m += __shfl_xor(m, s);
    if (lane == 0) flag[0] = (m >= 32) ? 0 : 1;
}

// ---------------------------------------------------------------- convert (elementwise)
__global__ __launch_bounds__(256) void convert_vec(
    const void* __restrict__ src, u16* __restrict__ dst, int n, const int* __restrict__ flag)
{
    int stride = gridDim.x * 256;
    int i0 = blockIdx.x * 256 + threadIdx.x;
    if (*flag) {
        const float* s = (const float*)src;
        for (int i = i0; i < n; i += stride) dst[i] = f2bf(s[i]);
    } else {
        const u16* s = (const u16*)src;
        for (int i = i0; i < n; i += stride) dst[i] = s[i];
    }
}

// ---------------------------------------------------------------- transpose+convert
// out[n][k] = cvt(in[k][n]), 1024x1024, 4 matrices via blockIdx.z
__global__ __launch_bounds__(256) void transpose_cvt(
    const void* __restrict__ w0, const void* __restrict__ w1,
    const void* __restrict__ w2, const void* __restrict__ w3,
    u16* __restrict__ o0, u16* __restrict__ o1,
    u16* __restrict__ o2, u16* __restrict__ o3, const int* __restrict__ flag)
{
    const void* in; u16* out;
    switch (blockIdx.z) {
        case 0: in = w0; out = o0; break;
        case 1: in = w1; out = o1; break;
        case 2: in = w2; out = o2; break;
        default: in = w3; out = o3; break;
    }
    int n  = blockIdx.x * 64 + (threadIdx.x & 63);
    int kb = blockIdx.y * 32 + (threadIdx.x >> 6) * 8;
    u16 v[8];
    if (*flag) {
        const float* f = (const float*)in;
#pragma unroll
        for (int j = 0; j < 8; ++j) v[j] = f2bf(f[(size_t)(kb + j) * 1024 + n]);
    } else {
        const u16* s = (const u16*)in;
#pragma unroll
        for (int j = 0; j < 8; ++j) v[j] = s[(size_t)(kb + j) * 1024 + n];
    }
    uint4 pk;
    pk.x = (unsigned)v[0] | ((unsigned)v[1] << 16);
    pk.y = (unsigned)v[2] | ((unsigned)v[3] << 16);
    pk.z = (unsigned)v[4] | ((unsigned)v[5] << 16);
    pk.w = (unsigned)v[6] | ((unsigned)v[7] << 16);
    *(uint4*)(out + (size_t)n * 1024 + kb) = pk;
}

// ---------------------------------------------------------------- GEMM
// C = A[M][K] * B, BT = B^T ([N][K]); A,BT bf16, f32 acc.
// fp32_out==0: store bf16. fp32_out==1: store fp32 if *flag else bf16.
__global__ __launch_bounds__(256) void gemm_bt(
    const u16* __restrict__ A, const u16* __restrict__ BT, void* __restrict__ C,
    int M, int Nn, int K, const int* __restrict__ flag, int fp32_out)
{
    __shared__ alignas(16) u16 As[128 * 32];
    __shared__ alignas(16) u16 Bs[128 * 32];
    const int tid  = threadIdx.x;
    const int lane = tid & 63;
    const int wv   = tid >> 6;
    const int wm   = wv >> 1, wn = wv & 1;
    const int bm   = blockIdx.x * 128, bn = blockIdx.y * 128;
    const int fr   = lane & 15, fk = lane >> 4;

    f32x4 acc[4][4];
#pragma unroll
    for (int i = 0; i < 4; ++i)
#pragma unroll
        for (int j = 0; j < 4; ++j) acc[i][j] = (f32x4){0.f, 0.f, 0.f, 0.f};

    for (int k0 = 0; k0 < K; k0 += 32) {
        __syncthreads();
#pragma unroll
        for (int p = 0; p < 2; ++p) {
            int i = tid + p * 256;
            int r = i >> 2, kc = (i & 3) << 3;
            gload_lds16(A  + (size_t)(bm + r) * K + k0 + kc,
                        (char*)As + (size_t)(wv * 64 + p * 256) * 16);
            gload_lds16(BT + (size_t)(bn + r) * K + k0 + kc,
                        (char*)Bs + (size_t)(wv * 64 + p * 256) * 16);
        }
        __syncthreads();
        bf16x8 af[4], bfr[4];
#pragma unroll
        for (int mi = 0; mi < 4; ++mi)
            af[mi] = *(const bf16x8*)(As + (wm * 64 + mi * 16 + fr) * 32 + fk * 8);
#pragma unroll
        for (int ni = 0; ni < 4; ++ni)
            bfr[ni] = *(const bf16x8*)(Bs + (wn * 64 + ni * 16 + fr) * 32 + fk * 8);
#pragma unroll
        for (int mi = 0; mi < 4; ++mi)
#pragma unroll
            for (int ni = 0; ni < 4; ++ni)
                acc[mi][ni] = __builtin_amdgcn_mfma_f32_16x16x32_bf16(
                    af[mi], bfr[ni], acc[mi][ni], 0, 0, 0);
    }
    bool f32st = fp32_out && (*flag);
    if (f32st) {
        float* Cf = (float*)C;
#pragma unroll
        for (int mi = 0; mi < 4; ++mi)
#pragma unroll
            for (int ni = 0; ni < 4; ++ni)
#pragma unroll
                for (int j = 0; j < 4; ++j) {
                    int row = bm + wm * 64 + mi * 16 + fk * 4 + j;
                    int col = bn + wn * 64 + ni * 16 + fr;
                    Cf[(size_t)row * Nn + col] = acc[mi][ni][j];
                }
    } else {
        u16* Cb = (u16*)C;
#pragma unroll
        for (int mi = 0; mi < 4; ++mi)
#pragma unroll
            for (int ni = 0; ni < 4; ++ni)
#pragma unroll
                for (int j = 0; j < 4; ++j) {
                    int row = bm + wm * 64 + mi * 16 + fk * 4 + j;
                    int col = bn + wn * 64 + ni * 16 + fr;
                    Cb[(size_t)row * Nn + col] = f2bf(acc[mi][ni][j]);
                }
    }
}

// ---------------------------------------------------------------- beta = sigmoid(x @ Wbeta)
// x [8192][1024] bf16, Wb [1024][4] bf16 -> beta [B*H][N] f32 ; one wave per row
__global__ __launch_bounds__(256) void beta_kernel(
    const u16* __restrict__ x, const u16* __restrict__ Wb, float* __restrict__ beta)
{
    int row  = blockIdx.x * 4 + (threadIdx.x >> 6);
    int lane = threadIdx.x & 63;
    const u16* xr = x + (size_t)row * 1024;
    float a0 = 0.f, a1 = 0.f, a2 = 0.f, a3 = 0.f;
    for (int c = 0; c < 16; ++c) {
        int k = c * 64 + lane;
        float xv = bf2f(xr[k]);
        uint2 w = *(const uint2*)(Wb + (size_t)k * 4);
        a0 += xv * bf2f(w.x);
        a1 += xv * bf2f(w.x >> 16);
        a2 += xv * bf2f(w.y);
        a3 += xv * bf2f(w.y >> 16);
    }
#pragma unroll
    for (int m = 1; m < 64; m <<= 1) {
        a0 += __shfl_xor(a0, m); a1 += __shfl_xor(a1, m);
        a2 += __shfl_xor(a2, m); a3 += __shfl_xor(a3, m);
    }
    if (lane == 0) {
        int b = row >> 10, nn = row & 1023;
        beta[(size_t)(b * 4 + 0) * 1024 + nn] = 1.f / (1.f + expf(-a0));
        beta[(size_t)(b * 4 + 1) * 1024 + nn] = 1.f / (1.f + expf(-a1));
        beta[(size_t)(b * 4 + 2) * 1024 + nn] = 1.f / (1.f + expf(-a2));
        beta[(size_t)(b * 4 + 3) * 1024 + nn] = 1.f / (1.f + expf(-a3));
    }
}

// ---------------------------------------------------------------- per-head l2norm (in place)
__global__ __launch_bounds__(256) void l2norm_qk(u16* __restrict__ Q, u16* __restrict__ K)
{
    u16* base = blockIdx.y ? K : Q;
    int w    = blockIdx.x * 4 + (threadIdx.x >> 6);   // row*4 + h
    int lane = threadIdx.x & 63;
    u16* p = base + (size_t)(w >> 2) * 1024 + (w & 3) * 256 + lane * 4;
    uint2 u = *(const uint2*)p;
    float f0 = bf2f(u.x), f1 = bf2f(u.x >> 16), f2 = bf2f(u.y), f3 = bf2f(u.y >> 16);
    float ss = f0 * f0 + f1 * f1 + f2 * f2 + f3 * f3;
#pragma unroll
    for (int m = 1; m < 64; m <<= 1) ss += __shfl_xor(ss, m);
    float inv = rsqrtf(ss + 1e-20f);
    uint2 o;
    o.x = (unsigned)f2bf(f0 * inv) | ((unsigned)f2bf(f1 * inv) << 16);
    o.y = (unsigned)f2bf(f2 * inv) | ((unsigned)f2bf(f3 * inv) << 16);
    *(uint2*)p = o;
}

// ---------------------------------------------------------------- delta-rule scan
// 256 blocks: (bh, dv-block of 32). 512 threads: tid = g*32 + dv, g in [0,16).
// Thread state S[i] = S[g*16+i][dv] (fp32). o_t written bf16 IN PLACE into V.
#define CH 8
__global__ __launch_bounds__(512) void scan_kernel(
    const u16* __restrict__ Qn, const u16* __restrict__ Kn,
    u16* V, const float* __restrict__ beta)
{
    const int bh  = blockIdx.x >> 3;
    const int dvb = blockIdx.x & 7;
    const int b   = bh >> 2, h = bh & 3;
    const int tid = threadIdx.x;
    const int g   = tid >> 5;      // 0..15
    const int dv  = tid & 31;

    __shared__ alignas(16) float kbuf[2][CH][256];
    __shared__ alignas(16) float qbuf[2][CH][256];
    __shared__ float vbuf[2][CH][32];
    __shared__ float bbuf[2][CH];
    __shared__ float red[2][32][9];
    __shared__ float ost[CH][32][9];

    float S[16];
#pragma unroll
    for (int i = 0; i < 16; ++i) S[i] = 0.f;

    const size_t rowbase = ((size_t)b * 1024) * 1024 + (size_t)h * 256;
    const int s_s = tid >> 6;            // k/q staging step
    const int s_d = (tid & 63) * 4;      // 4 bf16 per thread

    uint2 kreg, qreg; u16 vreg = 0; float breg = 0.f;
    auto load_chunk = [&](int t0) {
        size_t rk = rowbase + (size_t)(t0 + s_s) * 1024 + s_d;
        kreg = *(const uint2*)(Kn + rk);
        qreg = *(const uint2*)(Qn + rk);
        if (tid < 256)
            vreg = V[rowbase + (size_t)(t0 + (tid >> 5)) * 1024 + dvb * 32 + (tid & 31)];
        if (tid < CH) breg = beta[(size_t)bh * 1024 + t0 + tid];
    };
    auto write_chunk = [&](int bf) {
        f32x4 kv, qv;
        kv.x = bf2f(kreg.x); kv.y = bf2f(kreg.x >> 16);
        kv.z = bf2f(kreg.y); kv.w = bf2f(kreg.y >> 16);
        qv.x = bf2f(qreg.x); qv.y = bf2f(qreg.x >> 16);
        qv.z = bf2f(qreg.y); qv.w = bf2f(qreg.y >> 16);
        *(f32x4*)&kbuf[bf][s_s][s_d] = kv;
        *(f32x4*)&qbuf[bf][s_s][s_d] = qv;
        if (tid < 256) vbuf[bf][tid >> 5][tid & 31] = bf2f(vreg);
        if (tid < CH) bbuf[bf][tid] = breg;
    };

    load_chunk(0);
    write_chunk(0);
    __syncthreads();

    int buf = 0;
    const int NCH = 1024 / CH;
    for (int c = 0; c < NCH; ++c) {
        if (c + 1 < NCH) load_chunk((c + 1) * CH);
#pragma unroll
        for (int s = 0; s < CH; ++s) {
            const float* kp = &kbuf[buf][s][g * 16];
            f32x4 ka = *(const f32x4*)(kp);
            f32x4 kb = *(const f32x4*)(kp + 4);
            f32x4 kc = *(const f32x4*)(kp + 8);
            f32x4 kd = *(const f32x4*)(kp + 12);
            float pr = ka.x * S[0] + ka.y * S[1] + ka.z * S[2] + ka.w * S[3]
                     + kb.x * S[4] + kb.y * S[5] + kb.z * S[6] + kb.w * S[7]
                     + kc.x * S[8] + kc.y * S[9] + kc.z * S[10] + kc.w * S[11]
                     + kd.x * S[12] + kd.y * S[13] + kd.z * S[14] + kd.w * S[15];
            pr += __shfl_xor(pr, 32);
            if (!(g & 1)) red[s & 1][dv][g >> 1] = pr;
            __syncthreads();
            const float* rp = red[s & 1][dv];
            float pred = ((rp[0] + rp[1]) + (rp[2] + rp[3]))
                       + ((rp[4] + rp[5]) + (rp[6] + rp[7]));
            float err = bbuf[buf][s] * (vbuf[buf][s][dv] - pred);
            S[0] += ka.x * err;  S[1] += ka.y * err;  S[2] += ka.z * err;  S[3] += ka.w * err;
            S[4] += kb.x * err;  S[5] += kb.y * err;  S[6] += kb.z * err;  S[7] += kb.w * err;
            S[8] += kc.x * err;  S[9] += kc.y * err;  S[10] += kc.z * err; S[11] += kc.w * err;
            S[12] += kd.x * err; S[13] += kd.y * err; S[14] += kd.z * err; S[15] += kd.w * err;
            const float* qp = &qbuf[buf][s][g * 16];
            f32x4 qa = *(const f32x4*)(qp);
            f32x4 qb = *(const f32x4*)(qp + 4);
            f32x4 qc = *(const f32x4*)(qp + 8);
            f32x4 qd = *(const f32x4*)(qp + 12);
            float oo = qa.x * S[0] + qa.y * S[1] + qa.z * S[2] + qa.w * S[3]
                     + qb.x * S[4] + qb.y * S[5] + qb.z * S[6] + qb.w * S[7]
                     + qc.x * S[8] + qc.y * S[9] + qc.z * S[10] + qc.w * S[11]
                     + qd.x * S[12] + qd.y * S[13] + qd.z * S[14] + qd.w * S[15];
            oo += __shfl_xor(oo, 32);
            if (!(g & 1)) ost[s][dv][g >> 1] = oo;
        }
        __syncthreads();
        if (tid < 256) {
            int s = tid >> 5, d2 = tid & 31;
            const float* op = ost[s][d2];
            float o = ((op[0] + op[1]) + (op[2] + op[3]))
                    + ((op[4] + op[5]) + (op[6] + op[7]));
            V[rowbase + (size_t)(c * CH + s) * 1024 + dvb * 32 + d2] = f2bf(o);
        }
        if (c + 1 < NCH) write_chunk(buf ^ 1);
        __syncthreads();
        buf ^= 1;
    }
}

// ---------------------------------------------------------------- RMSNorm over Dv, in place
__global__ __launch_bounds__(256) void rmsnorm_o(u16* V, const u16* __restrict__ gn)
{
    int w    = blockIdx.x * 4 + (threadIdx.x >> 6);   // (b*1024+t)*4 + h
    int lane = threadIdx.x & 63;
    u16* p = V + (size_t)(w >> 2) * 1024 + (w & 3) * 256 + lane * 4;
    uint2 u = *(const uint2*)p;
    float f0 = bf2f(u.x), f1 = bf2f(u.x >> 16), f2 = bf2f(u.y), f3 = bf2f(u.y >> 16);
    float ss = f0 * f0 + f1 * f1 + f2 * f2 + f3 * f3;
#pragma unroll
    for (int m = 1; m < 64; m <<= 1) ss += __shfl_xor(ss, m);
    float sc = rsqrtf(ss * (1.0f / 256.0f) + 1e-5f);
    int d0 = lane * 4;
    uint2 gu = *(const uint2*)(gn + d0);
    float g0 = bf2f(gu.x), g1 = bf2f(gu.x >> 16), g2 = bf2f(gu.y), g3 = bf2f(gu.y >> 16);
    uint2 o;
    o.x = (unsigned)f2bf(f0 * sc * g0) | ((unsigned)f2bf(f1 * sc * g1) << 16);
    o.y = (unsigned)f2bf(f2 * sc * g2) | ((unsigned)f2bf(f3 * sc * g3) << 16);
    *(uint2*)p = o;
}

// ---------------------------------------------------------------- launch
extern "C" void kernel_launch(void* const* d_in, const int* in_sizes, int n_in,
                              void* d_out, int out_size, void* d_ws, size_t ws_size,
                              hipStream_t stream)
{
    const void* x  = d_in[0];
    const void* Wq = d_in[1];
    const void* Wk = d_in[2];
    const void* Wv = d_in[3];
    const void* Wb = d_in[4];
    const void* Wo = d_in[5];
    const void* gn = d_in[6];

    char* ws = (char*)d_ws;
    const size_t OFF_FLAG = 0;                        // 4 KB block
    const size_t OFF_WBC  = 4096;                     // 8 KB (Wbeta bf16)
    const size_t OFF_GNC  = OFF_WBC + 8192;           // 4 KB block (g_norm bf16)
    const size_t OFF_XB   = OFF_GNC + 4096;           // 16 MB (x bf16)
    const size_t OFF_WQT  = OFF_XB + 16777216;        // 2 MB
    const size_t OFF_WKT  = OFF_WQT + 2097152;        // 2 MB
    const size_t OFF_WVT  = OFF_WKT + 2097152;        // 2 MB
    const size_t OFF_WOT  = OFF_WVT + 2097152;        // 2 MB
    const size_t OFF_Q    = OFF_WOT + 2097152;        // 16 MB
    const size_t OFF_K    = OFF_Q + 16777216;         // 16 MB
    const size_t OFF_V    = OFF_K + 16777216;         // 16 MB
    const size_t OFF_BP   = OFF_V + 16777216;         // 128 KB  -> ~72.6 MB total

    int*   flag = (int*)(ws + OFF_FLAG);
    u16*   Wbc  = (u16*)(ws + OFF_WBC);
    u16*   gnc  = (u16*)(ws + OFF_GNC);
    u16*   Xb   = (u16*)(ws + OFF_XB);
    u16*   wqT  = (u16*)(ws + OFF_WQT);
    u16*   wkT  = (u16*)(ws + OFF_WKT);
    u16*   wvT  = (u16*)(ws + OFF_WVT);
    u16*   woT  = (u16*)(ws + OFF_WOT);
    u16*   Qb   = (u16*)(ws + OFF_Q);
    u16*   Kb   = (u16*)(ws + OFF_K);
    u16*   Vb   = (u16*)(ws + OFF_V);
    float* Bp   = (float*)(ws + OFF_BP);

    detect_dtype<<<1, 64, 0, stream>>>((const unsigned*)Wq, flag);
    convert_vec<<<2048, 256, 0, stream>>>(x, Xb, 8388608, flag);
    convert_vec<<<16, 256, 0, stream>>>(Wb, Wbc, 4096, flag);
    convert_vec<<<1, 256, 0, stream>>>(gn, gnc, 256, flag);
    transpose_cvt<<<dim3(16, 32, 4), 256, 0, stream>>>(Wq, Wk, Wv, Wo, wqT, wkT, wvT, woT, flag);

    gemm_bt<<<dim3(64, 8), 256, 0, stream>>>(Xb, wqT, Qb, 8192, 1024, 1024, flag, 0);
    gemm_bt<<<dim3(64, 8), 256, 0, stream>>>(Xb, wkT, Kb, 8192, 1024, 1024, flag, 0);
    gemm_bt<<<dim3(64, 8), 256, 0, stream>>>(Xb, wvT, Vb, 8192, 1024, 1024, flag, 0);
    beta_kernel<<<2048, 256, 0, stream>>>(Xb, Wbc, Bp);
    l2norm_qk<<<dim3(8192, 2), 256, 0, stream>>>(Qb, Kb);
    scan_kernel<<<256, 512, 0, stream>>>(Qb, Kb, Vb, Bp);
    rmsnorm_o<<<8192, 256, 0, stream>>>(Vb, gnc);
    gemm_bt<<<dim3(64, 8), 256, 0, stream>>>(Vb, woT, d_out, 8192, 1024, 1024, flag, 1);
}

// Round 4
// 622.113 us; speedup vs baseline: 1.0454x; 1.0454x over previous
//
#include <hip/hip_runtime.h>
#include <hip/hip_bf16.h>
#include <math.h>

typedef unsigned short u16;
typedef __attribute__((ext_vector_type(8))) __bf16 bf16x8;
typedef __attribute__((ext_vector_type(4))) float f32x4;

__device__ __forceinline__ float bf2f(unsigned int u) {
    union { unsigned int i; float f; } x;
    x.i = (u & 0xffffu) << 16;
    return x.f;
}
__device__ __forceinline__ u16 f2bf(float f) {
    unsigned int i = __float_as_uint(f);
    unsigned int r = (i + 0x7fffu + ((i >> 16) & 1u)) >> 16;
    return (u16)r;
}

__device__ __forceinline__ void gload_lds16(const void* g, void* l) {
    __builtin_amdgcn_global_load_lds((const __attribute__((address_space(1))) void*)g,
                                     (__attribute__((address_space(3))) void*)l, 16, 0, 0);
}

// ---------------------------------------------------------------- dtype detect
__global__ void detect_dtype(const unsigned* __restrict__ wq, int* __restrict__ flag)
{
    int lane = threadIdx.x;   // 64 threads
    unsigned lo = wq[lane] & 0xffffu;
    unsigned e = (lo >> 7) & 0xffu;
    int m = (e >= 0x6e && e <= 0x7e) ? 1 : 0;
#pragma unroll
    for (int s = 1; s < 64; s <<= 1) m += __shfl_xor(m, s);
    if (lane == 0) flag[0] = (m >= 32) ? 0 : 1;
}

// ---------------------------------------------------------------- convert (elementwise)
__global__ __launch_bounds__(256) void convert_vec(
    const void* __restrict__ src, u16* __restrict__ dst, int n, const int* __restrict__ flag)
{
    int stride = gridDim.x * 256;
    int i0 = blockIdx.x * 256 + threadIdx.x;
    if (*flag) {
        const float* s = (const float*)src;
        for (int i = i0; i < n; i += stride) dst[i] = f2bf(s[i]);
    } else {
        const u16* s = (const u16*)src;
        for (int i = i0; i < n; i += stride) dst[i] = s[i];
    }
}

// ---------------------------------------------------------------- transpose+convert
__global__ __launch_bounds__(256) void transpose_cvt(
    const void* __restrict__ w0, const void* __restrict__ w1,
    const void* __restrict__ w2, const void* __restrict__ w3,
    u16* __restrict__ o0, u16* __restrict__ o1,
    u16* __restrict__ o2, u16* __restrict__ o3, const int* __restrict__ flag)
{
    const void* in; u16* out;
    switch (blockIdx.z) {
        case 0: in = w0; out = o0; break;
        case 1: in = w1; out = o1; break;
        case 2: in = w2; out = o2; break;
        default: in = w3; out = o3; break;
    }
    int n  = blockIdx.x * 64 + (threadIdx.x & 63);
    int kb = blockIdx.y * 32 + (threadIdx.x >> 6) * 8;
    u16 v[8];
    if (*flag) {
        const float* f = (const float*)in;
#pragma unroll
        for (int j = 0; j < 8; ++j) v[j] = f2bf(f[(size_t)(kb + j) * 1024 + n]);
    } else {
        const u16* s = (const u16*)in;
#pragma unroll
        for (int j = 0; j < 8; ++j) v[j] = s[(size_t)(kb + j) * 1024 + n];
    }
    uint4 pk;
    pk.x = (unsigned)v[0] | ((unsigned)v[1] << 16);
    pk.y = (unsigned)v[2] | ((unsigned)v[3] << 16);
    pk.z = (unsigned)v[4] | ((unsigned)v[5] << 16);
    pk.w = (unsigned)v[6] | ((unsigned)v[7] << 16);
    *(uint4*)(out + (size_t)n * 1024 + kb) = pk;
}

// ---------------------------------------------------------------- GEMM (m97-style)
__global__ __launch_bounds__(256) void gemm_bt(
    const u16* __restrict__ A, const u16* __restrict__ BT, void* __restrict__ C,
    int M, int Nn, int K, const int* __restrict__ flag, int fp32_out)
{
    __shared__ alignas(16) u16 As[128 * 32];
    __shared__ alignas(16) u16 Bs[128 * 32];
    const int tid  = threadIdx.x;
    const int lane = tid & 63;
    const int wv   = tid >> 6;
    const int wm   = wv >> 1, wn = wv & 1;
    const int bm   = blockIdx.x * 128, bn = blockIdx.y * 128;
    const int fr   = lane & 15, fk = lane >> 4;

    f32x4 acc[4][4];
#pragma unroll
    for (int i = 0; i < 4; ++i)
#pragma unroll
        for (int j = 0; j < 4; ++j) acc[i][j] = (f32x4){0.f, 0.f, 0.f, 0.f};

    for (int k0 = 0; k0 < K; k0 += 32) {
        __syncthreads();
#pragma unroll
        for (int p = 0; p < 2; ++p) {
            int i = tid + p * 256;
            int r = i >> 2, kc = (i & 3) << 3;
            gload_lds16(A  + (size_t)(bm + r) * K + k0 + kc,
                        (char*)As + (size_t)(wv * 64 + p * 256) * 16);
            gload_lds16(BT + (size_t)(bn + r) * K + k0 + kc,
                        (char*)Bs + (size_t)(wv * 64 + p * 256) * 16);
        }
        __syncthreads();
        bf16x8 af[4], bfr[4];
#pragma unroll
        for (int mi = 0; mi < 4; ++mi)
            af[mi] = *(const bf16x8*)(As + (wm * 64 + mi * 16 + fr) * 32 + fk * 8);
#pragma unroll
        for (int ni = 0; ni < 4; ++ni)
            bfr[ni] = *(const bf16x8*)(Bs + (wn * 64 + ni * 16 + fr) * 32 + fk * 8);
#pragma unroll
        for (int mi = 0; mi < 4; ++mi)
#pragma unroll
            for (int ni = 0; ni < 4; ++ni)
                acc[mi][ni] = __builtin_amdgcn_mfma_f32_16x16x32_bf16(
                    af[mi], bfr[ni], acc[mi][ni], 0, 0, 0);
    }
    bool f32st = fp32_out && (*flag);
    if (f32st) {
        float* Cf = (float*)C;
#pragma unroll
        for (int mi = 0; mi < 4; ++mi)
#pragma unroll
            for (int ni = 0; ni < 4; ++ni)
#pragma unroll
                for (int j = 0; j < 4; ++j) {
                    int row = bm + wm * 64 + mi * 16 + fk * 4 + j;
                    int col = bn + wn * 64 + ni * 16 + fr;
                    Cf[(size_t)row * Nn + col] = acc[mi][ni][j];
                }
    } else {
        u16* Cb = (u16*)C;
#pragma unroll
        for (int mi = 0; mi < 4; ++mi)
#pragma unroll
            for (int ni = 0; ni < 4; ++ni)
#pragma unroll
                for (int j = 0; j < 4; ++j) {
                    int row = bm + wm * 64 + mi * 16 + fk * 4 + j;
                    int col = bn + wn * 64 + ni * 16 + fr;
                    Cb[(size_t)row * Nn + col] = f2bf(acc[mi][ni][j]);
                }
    }
}

// ---------------------------------------------------------------- beta = sigmoid(x @ Wbeta)
__global__ __launch_bounds__(256) void beta_kernel(
    const u16* __restrict__ x, const u16* __restrict__ Wb, float* __restrict__ beta)
{
    int row  = blockIdx.x * 4 + (threadIdx.x >> 6);
    int lane = threadIdx.x & 63;
    const u16* xr = x + (size_t)row * 1024;
    float a0 = 0.f, a1 = 0.f, a2 = 0.f, a3 = 0.f;
    for (int c = 0; c < 16; ++c) {
        int k = c * 64 + lane;
        float xv = bf2f(xr[k]);
        uint2 w = *(const uint2*)(Wb + (size_t)k * 4);
        a0 += xv * bf2f(w.x);
        a1 += xv * bf2f(w.x >> 16);
        a2 += xv * bf2f(w.y);
        a3 += xv * bf2f(w.y >> 16);
    }
#pragma unroll
    for (int m = 1; m < 64; m <<= 1) {
        a0 += __shfl_xor(a0, m); a1 += __shfl_xor(a1, m);
        a2 += __shfl_xor(a2, m); a3 += __shfl_xor(a3, m);
    }
    if (lane == 0) {
        int b = row >> 10, nn = row & 1023;
        beta[(size_t)(b * 4 + 0) * 1024 + nn] = 1.f / (1.f + expf(-a0));
        beta[(size_t)(b * 4 + 1) * 1024 + nn] = 1.f / (1.f + expf(-a1));
        beta[(size_t)(b * 4 + 2) * 1024 + nn] = 1.f / (1.f + expf(-a2));
        beta[(size_t)(b * 4 + 3) * 1024 + nn] = 1.f / (1.f + expf(-a3));
    }
}

// ---------------------------------------------------------------- per-head l2norm (in place)
__global__ __launch_bounds__(256) void l2norm_qk(u16* __restrict__ Q, u16* __restrict__ K)
{
    u16* base = blockIdx.y ? K : Q;
    int w    = blockIdx.x * 4 + (threadIdx.x >> 6);   // row*4 + h
    int lane = threadIdx.x & 63;
    u16* p = base + (size_t)(w >> 2) * 1024 + (w & 3) * 256 + lane * 4;
    uint2 u = *(const uint2*)p;
    float f0 = bf2f(u.x), f1 = bf2f(u.x >> 16), f2 = bf2f(u.y), f3 = bf2f(u.y >> 16);
    float ss = f0 * f0 + f1 * f1 + f2 * f2 + f3 * f3;
#pragma unroll
    for (int m = 1; m < 64; m <<= 1) ss += __shfl_xor(ss, m);
    float inv = rsqrtf(ss + 1e-20f);
    uint2 o;
    o.x = (unsigned)f2bf(f0 * inv) | ((unsigned)f2bf(f1 * inv) << 16);
    o.y = (unsigned)f2bf(f2 * inv) | ((unsigned)f2bf(f3 * inv) << 16);
    *(uint2*)p = o;
}

// ---------------------------------------------------------------- delta-rule scan (wave-local)
// Grid (8, 32): blockIdx.x = dv-block of 32, blockIdx.y = bh. 256 threads = 4 waves.
// Wave wv owns dv columns dvb*32 + wv*8 .. +7. Lane = dvsub*8 + g8:
//   dv = dvb*32 + wv*8 + dvsub; S[j*4+e] = S_global[j*32 + g8*4 + e][dv], j<8.
// pred/out reduce over the 8-lane g8 group via 3 shfl_xor hops. NO per-step barrier;
// one __syncthreads per 8-step chunk (LDS double-buffer swap).
// o_t stored bf16 in place into V (disjoint rows/cols as in r3).
#define CH 8
__global__ __launch_bounds__(256) void scan_kernel(
    const u16* __restrict__ Qn, const u16* __restrict__ Kn,
    u16* V, const float* __restrict__ beta)
{
    const int dvb = blockIdx.x;        // 0..7
    const int bh  = blockIdx.y;        // 0..31
    const int b   = bh >> 2, h = bh & 3;
    const int tid = threadIdx.x;
    const int g8  = tid & 7;
    const int col32 = tid >> 3;        // wv*8 + dvsub, 0..31

    __shared__ alignas(16) float kbuf[2][CH][256];
    __shared__ alignas(16) float qbuf[2][CH][256];
    __shared__ float vbuf[2][CH][32];
    __shared__ float bbuf[2][CH];

    float S[32];
#pragma unroll
    for (int i = 0; i < 32; ++i) S[i] = 0.f;

    const size_t rowbase = ((size_t)b * 1024) * 1024 + (size_t)h * 256;
    const int s_s = tid >> 5;          // staging step 0..7
    const int c32 = tid & 31;          // staging column group

    uint2 ka_r, kb_r, qa_r, qb_r; u16 vreg = 0; float breg = 0.f;
    auto load_chunk = [&](int t0) {
        size_t rk = rowbase + (size_t)(t0 + s_s) * 1024 + c32 * 4;
        ka_r = *(const uint2*)(Kn + rk);
        kb_r = *(const uint2*)(Kn + rk + 128);
        qa_r = *(const uint2*)(Qn + rk);
        qb_r = *(const uint2*)(Qn + rk + 128);
        vreg = V[rowbase + (size_t)(t0 + s_s) * 1024 + dvb * 32 + c32];
        if (tid < CH) breg = beta[(size_t)bh * 1024 + t0 + tid];
    };
    auto cvt4 = [](uint2 u) {
        f32x4 r;
        r.x = bf2f(u.x); r.y = bf2f(u.x >> 16);
        r.z = bf2f(u.y); r.w = bf2f(u.y >> 16);
        return r;
    };
    auto write_chunk = [&](int bf) {
        *(f32x4*)&kbuf[bf][s_s][c32 * 4]       = cvt4(ka_r);
        *(f32x4*)&kbuf[bf][s_s][128 + c32 * 4] = cvt4(kb_r);
        *(f32x4*)&qbuf[bf][s_s][c32 * 4]       = cvt4(qa_r);
        *(f32x4*)&qbuf[bf][s_s][128 + c32 * 4] = cvt4(qb_r);
        vbuf[bf][s_s][c32] = bf2f(vreg);
        if (tid < CH) bbuf[bf][tid] = breg;
    };

    load_chunk(0);
    write_chunk(0);
    __syncthreads();

    float okeep = 0.f;
    int buf = 0;
    const int NCH = 1024 / CH;
    for (int c = 0; c < NCH; ++c) {
        if (c + 1 < NCH) load_chunk((c + 1) * CH);
#pragma unroll
        for (int s = 0; s < CH; ++s) {
            const float* krow = kbuf[buf][s];
            const float* qrow = qbuf[buf][s];
            f32x4 kf[8];
#pragma unroll
            for (int j = 0; j < 8; ++j)
                kf[j] = *(const f32x4*)(krow + j * 32 + g8 * 4);
            float pr = 0.f;
#pragma unroll
            for (int j = 0; j < 8; ++j)
                pr += kf[j].x * S[j*4+0] + kf[j].y * S[j*4+1]
                    + kf[j].z * S[j*4+2] + kf[j].w * S[j*4+3];
            pr += __shfl_xor(pr, 1);
            pr += __shfl_xor(pr, 2);
            pr += __shfl_xor(pr, 4);
            float err = bbuf[buf][s] * (vbuf[buf][s][col32] - pr);
#pragma unroll
            for (int j = 0; j < 8; ++j) {
                S[j*4+0] += kf[j].x * err;
                S[j*4+1] += kf[j].y * err;
                S[j*4+2] += kf[j].z * err;
                S[j*4+3] += kf[j].w * err;
            }
            f32x4 qf[8];
#pragma unroll
            for (int j = 0; j < 8; ++j)
                qf[j] = *(const f32x4*)(qrow + j * 32 + g8 * 4);
            float oo = 0.f;
#pragma unroll
            for (int j = 0; j < 8; ++j)
                oo += qf[j].x * S[j*4+0] + qf[j].y * S[j*4+1]
                    + qf[j].z * S[j*4+2] + qf[j].w * S[j*4+3];
            oo += __shfl_xor(oo, 1);
            oo += __shfl_xor(oo, 2);
            oo += __shfl_xor(oo, 4);
            okeep = (g8 == s) ? oo : okeep;
        }
        // store chunk outputs: lane holds o for step g8, column col32
        V[rowbase + (size_t)(c * CH + g8) * 1024 + dvb * 32 + col32] = f2bf(okeep);
        if (c + 1 < NCH) write_chunk(buf ^ 1);
        __syncthreads();
        buf ^= 1;
    }
}

// ---------------------------------------------------------------- RMSNorm over Dv, in place
__global__ __launch_bounds__(256) void rmsnorm_o(u16* V, const u16* __restrict__ gn)
{
    int w    = blockIdx.x * 4 + (threadIdx.x >> 6);   // (b*1024+t)*4 + h
    int lane = threadIdx.x & 63;
    u16* p = V + (size_t)(w >> 2) * 1024 + (w & 3) * 256 + lane * 4;
    uint2 u = *(const uint2*)p;
    float f0 = bf2f(u.x), f1 = bf2f(u.x >> 16), f2 = bf2f(u.y), f3 = bf2f(u.y >> 16);
    float ss = f0 * f0 + f1 * f1 + f2 * f2 + f3 * f3;
#pragma unroll
    for (int m = 1; m < 64; m <<= 1) ss += __shfl_xor(ss, m);
    float sc = rsqrtf(ss * (1.0f / 256.0f) + 1e-5f);
    int d0 = lane * 4;
    uint2 gu = *(const uint2*)(gn + d0);
    float g0 = bf2f(gu.x), g1 = bf2f(gu.x >> 16), g2 = bf2f(gu.y), g3 = bf2f(gu.y >> 16);
    uint2 o;
    o.x = (unsigned)f2bf(f0 * sc * g0) | ((unsigned)f2bf(f1 * sc * g1) << 16);
    o.y = (unsigned)f2bf(f2 * sc * g2) | ((unsigned)f2bf(f3 * sc * g3) << 16);
    *(uint2*)p = o;
}

// ---------------------------------------------------------------- launch
extern "C" void kernel_launch(void* const* d_in, const int* in_sizes, int n_in,
                              void* d_out, int out_size, void* d_ws, size_t ws_size,
                              hipStream_t stream)
{
    const void* x  = d_in[0];
    const void* Wq = d_in[1];
    const void* Wk = d_in[2];
    const void* Wv = d_in[3];
    const void* Wb = d_in[4];
    const void* Wo = d_in[5];
    const void* gn = d_in[6];

    char* ws = (char*)d_ws;
    const size_t OFF_FLAG = 0;                        // 4 KB block
    const size_t OFF_WBC  = 4096;                     // 8 KB (Wbeta bf16)
    const size_t OFF_GNC  = OFF_WBC + 8192;           // 4 KB block (g_norm bf16)
    const size_t OFF_XB   = OFF_GNC + 4096;           // 16 MB (x bf16)
    const size_t OFF_WQT  = OFF_XB + 16777216;        // 2 MB
    const size_t OFF_WKT  = OFF_WQT + 2097152;        // 2 MB
    const size_t OFF_WVT  = OFF_WKT + 2097152;        // 2 MB
    const size_t OFF_WOT  = OFF_WVT + 2097152;        // 2 MB
    const size_t OFF_Q    = OFF_WOT + 2097152;        // 16 MB
    const size_t OFF_K    = OFF_Q + 16777216;         // 16 MB
    const size_t OFF_V    = OFF_K + 16777216;         // 16 MB
    const size_t OFF_BP   = OFF_V + 16777216;         // 128 KB

    int*   flag = (int*)(ws + OFF_FLAG);
    u16*   Wbc  = (u16*)(ws + OFF_WBC);
    u16*   gnc  = (u16*)(ws + OFF_GNC);
    u16*   Xb   = (u16*)(ws + OFF_XB);
    u16*   wqT  = (u16*)(ws + OFF_WQT);
    u16*   wkT  = (u16*)(ws + OFF_WKT);
    u16*   wvT  = (u16*)(ws + OFF_WVT);
    u16*   woT  = (u16*)(ws + OFF_WOT);
    u16*   Qb   = (u16*)(ws + OFF_Q);
    u16*   Kb   = (u16*)(ws + OFF_K);
    u16*   Vb   = (u16*)(ws + OFF_V);
    float* Bp   = (float*)(ws + OFF_BP);

    detect_dtype<<<1, 64, 0, stream>>>((const unsigned*)Wq, flag);
    convert_vec<<<2048, 256, 0, stream>>>(x, Xb, 8388608, flag);
    convert_vec<<<16, 256, 0, stream>>>(Wb, Wbc, 4096, flag);
    convert_vec<<<1, 256, 0, stream>>>(gn, gnc, 256, flag);
    transpose_cvt<<<dim3(16, 32, 4), 256, 0, stream>>>(Wq, Wk, Wv, Wo, wqT, wkT, wvT, woT, flag);

    gemm_bt<<<dim3(64, 8), 256, 0, stream>>>(Xb, wqT, Qb, 8192, 1024, 1024, flag, 0);
    gemm_bt<<<dim3(64, 8), 256, 0, stream>>>(Xb, wkT, Kb, 8192, 1024, 1024, flag, 0);
    gemm_bt<<<dim3(64, 8), 256, 0, stream>>>(Xb, wvT, Vb, 8192, 1024, 1024, flag, 0);
    beta_kernel<<<2048, 256, 0, stream>>>(Xb, Wbc, Bp);
    l2norm_qk<<<dim3(8192, 2), 256, 0, stream>>>(Qb, Kb);
    scan_kernel<<<dim3(8, 32), 256, 0, stream>>>(Qb, Kb, Vb, Bp);
    rmsnorm_o<<<8192, 256, 0, stream>>>(Vb, gnc);
    gemm_bt<<<dim3(64, 8), 256, 0, stream>>>(Vb, woT, d_out, 8192, 1024, 1024, flag, 1);
}

// Round 5
// 439.631 us; speedup vs baseline: 1.4793x; 1.4151x over previous
//
#include <hip/hip_runtime.h>
#include <hip/hip_bf16.h>
#include <math.h>

typedef unsigned short u16;
typedef __attribute__((ext_vector_type(8))) __bf16 bf16x8;
typedef __attribute__((ext_vector_type(4))) float f32x4;

#define MFMA16 __builtin_amdgcn_mfma_f32_16x16x32_bf16

__device__ __forceinline__ float bf2f(unsigned int u) {
    union { unsigned int i; float f; } x;
    x.i = (u & 0xffffu) << 16;
    return x.f;
}
__device__ __forceinline__ u16 f2bf(float f) {
    unsigned int i = __float_as_uint(f);
    unsigned int r = (i + 0x7fffu + ((i >> 16) & 1u)) >> 16;
    return (u16)r;
}
__device__ __forceinline__ void split8(f32x4 a, f32x4 b, bf16x8& hi, bf16x8& lo) {
    union { bf16x8 v; u16 u[8]; } H, L;
    float f[8] = {a.x, a.y, a.z, a.w, b.x, b.y, b.z, b.w};
#pragma unroll
    for (int e = 0; e < 8; ++e) {
        u16 h = f2bf(f[e]);
        H.u[e] = h;
        L.u[e] = f2bf(f[e] - bf2f(h));
    }
    hi = H.v; lo = L.v;
}

__device__ __forceinline__ void gload_lds16(const void* g, void* l) {
    __builtin_amdgcn_global_load_lds((const __attribute__((address_space(1))) void*)g,
                                     (__attribute__((address_space(3))) void*)l, 16, 0, 0);
}

// ---------------------------------------------------------------- dtype detect
__global__ void detect_dtype(const unsigned* __restrict__ wq, int* __restrict__ flag)
{
    int lane = threadIdx.x;   // 64 threads
    unsigned lo = wq[lane] & 0xffffu;
    unsigned e = (lo >> 7) & 0xffu;
    int m = (e >= 0x6e && e <= 0x7e) ? 1 : 0;
#pragma unroll
    for (int s = 1; s < 64; s <<= 1) m += __shfl_xor(m, s);
    if (lane == 0) flag[0] = (m >= 32) ? 0 : 1;
}

// ---------------------------------------------------------------- convert (elementwise)
__global__ __launch_bounds__(256) void convert_vec(
    const void* __restrict__ src, u16* __restrict__ dst, int n, const int* __restrict__ flag)
{
    int stride = gridDim.x * 256;
    int i0 = blockIdx.x * 256 + threadIdx.x;
    if (*flag) {
        const float* s = (const float*)src;
        for (int i = i0; i < n; i += stride) dst[i] = f2bf(s[i]);
    } else {
        const u16* s = (const u16*)src;
        for (int i = i0; i < n; i += stride) dst[i] = s[i];
    }
}

// ---------------------------------------------------------------- transpose+convert
__global__ __launch_bounds__(256) void transpose_cvt(
    const void* __restrict__ w0, const void* __restrict__ w1,
    const void* __restrict__ w2, const void* __restrict__ w3,
    u16* __restrict__ o0, u16* __restrict__ o1,
    u16* __restrict__ o2, u16* __restrict__ o3, const int* __restrict__ flag)
{
    const void* in; u16* out;
    switch (blockIdx.z) {
        case 0: in = w0; out = o0; break;
        case 1: in = w1; out = o1; break;
        case 2: in = w2; out = o2; break;
        default: in = w3; out = o3; break;
    }
    int n  = blockIdx.x * 64 + (threadIdx.x & 63);
    int kb = blockIdx.y * 32 + (threadIdx.x >> 6) * 8;
    u16 v[8];
    if (*flag) {
        const float* f = (const float*)in;
#pragma unroll
        for (int j = 0; j < 8; ++j) v[j] = f2bf(f[(size_t)(kb + j) * 1024 + n]);
    } else {
        const u16* s = (const u16*)in;
#pragma unroll
        for (int j = 0; j < 8; ++j) v[j] = s[(size_t)(kb + j) * 1024 + n];
    }
    uint4 pk;
    pk.x = (unsigned)v[0] | ((unsigned)v[1] << 16);
    pk.y = (unsigned)v[2] | ((unsigned)v[3] << 16);
    pk.z = (unsigned)v[4] | ((unsigned)v[5] << 16);
    pk.w = (unsigned)v[6] | ((unsigned)v[7] << 16);
    *(uint4*)(out + (size_t)n * 1024 + kb) = pk;
}

// ---------------------------------------------------------------- GEMM (m97-style)
__global__ __launch_bounds__(256) void gemm_bt(
    const u16* __restrict__ A, const u16* __restrict__ BT, void* __restrict__ C,
    int M, int Nn, int K, const int* __restrict__ flag, int fp32_out)
{
    __shared__ alignas(16) u16 As[128 * 32];
    __shared__ alignas(16) u16 Bs[128 * 32];
    const int tid  = threadIdx.x;
    const int lane = tid & 63;
    const int wv   = tid >> 6;
    const int wm   = wv >> 1, wn = wv & 1;
    const int bm   = blockIdx.x * 128, bn = blockIdx.y * 128;
    const int fr   = lane & 15, fk = lane >> 4;

    f32x4 acc[4][4];
#pragma unroll
    for (int i = 0; i < 4; ++i)
#pragma unroll
        for (int j = 0; j < 4; ++j) acc[i][j] = (f32x4){0.f, 0.f, 0.f, 0.f};

    for (int k0 = 0; k0 < K; k0 += 32) {
        __syncthreads();
#pragma unroll
        for (int p = 0; p < 2; ++p) {
            int i = tid + p * 256;
            int r = i >> 2, kc = (i & 3) << 3;
            gload_lds16(A  + (size_t)(bm + r) * K + k0 + kc,
                        (char*)As + (size_t)(wv * 64 + p * 256) * 16);
            gload_lds16(BT + (size_t)(bn + r) * K + k0 + kc,
                        (char*)Bs + (size_t)(wv * 64 + p * 256) * 16);
        }
        __syncthreads();
        bf16x8 af[4], bfr[4];
#pragma unroll
        for (int mi = 0; mi < 4; ++mi)
            af[mi] = *(const bf16x8*)(As + (wm * 64 + mi * 16 + fr) * 32 + fk * 8);
#pragma unroll
        for (int ni = 0; ni < 4; ++ni)
            bfr[ni] = *(const bf16x8*)(Bs + (wn * 64 + ni * 16 + fr) * 32 + fk * 8);
#pragma unroll
        for (int mi = 0; mi < 4; ++mi)
#pragma unroll
            for (int ni = 0; ni < 4; ++ni)
                acc[mi][ni] = MFMA16(af[mi], bfr[ni], acc[mi][ni], 0, 0, 0);
    }
    bool f32st = fp32_out && (*flag);
    if (f32st) {
        float* Cf = (float*)C;
#pragma unroll
        for (int mi = 0; mi < 4; ++mi)
#pragma unroll
            for (int ni = 0; ni < 4; ++ni)
#pragma unroll
                for (int j = 0; j < 4; ++j) {
                    int row = bm + wm * 64 + mi * 16 + fk * 4 + j;
                    int col = bn + wn * 64 + ni * 16 + fr;
                    Cf[(size_t)row * Nn + col] = acc[mi][ni][j];
                }
    } else {
        u16* Cb = (u16*)C;
#pragma unroll
        for (int mi = 0; mi < 4; ++mi)
#pragma unroll
            for (int ni = 0; ni < 4; ++ni)
#pragma unroll
                for (int j = 0; j < 4; ++j) {
                    int row = bm + wm * 64 + mi * 16 + fk * 4 + j;
                    int col = bn + wn * 64 + ni * 16 + fr;
                    Cb[(size_t)row * Nn + col] = f2bf(acc[mi][ni][j]);
                }
    }
}

// ---------------------------------------------------------------- beta = sigmoid(x @ Wbeta)
__global__ __launch_bounds__(256) void beta_kernel(
    const u16* __restrict__ x, const u16* __restrict__ Wb, float* __restrict__ beta)
{
    int row  = blockIdx.x * 4 + (threadIdx.x >> 6);
    int lane = threadIdx.x & 63;
    const u16* xr = x + (size_t)row * 1024;
    float a0 = 0.f, a1 = 0.f, a2 = 0.f, a3 = 0.f;
    for (int c = 0; c < 16; ++c) {
        int k = c * 64 + lane;
        float xv = bf2f(xr[k]);
        uint2 w = *(const uint2*)(Wb + (size_t)k * 4);
        a0 += xv * bf2f(w.x);
        a1 += xv * bf2f(w.x >> 16);
        a2 += xv * bf2f(w.y);
        a3 += xv * bf2f(w.y >> 16);
    }
#pragma unroll
    for (int m = 1; m < 64; m <<= 1) {
        a0 += __shfl_xor(a0, m); a1 += __shfl_xor(a1, m);
        a2 += __shfl_xor(a2, m); a3 += __shfl_xor(a3, m);
    }
    if (lane == 0) {
        int b = row >> 10, nn = row & 1023;
        beta[(size_t)(b * 4 + 0) * 1024 + nn] = 1.f / (1.f + expf(-a0));
        beta[(size_t)(b * 4 + 1) * 1024 + nn] = 1.f / (1.f + expf(-a1));
        beta[(size_t)(b * 4 + 2) * 1024 + nn] = 1.f / (1.f + expf(-a2));
        beta[(size_t)(b * 4 + 3) * 1024 + nn] = 1.f / (1.f + expf(-a3));
    }
}

// ---------------------------------------------------------------- per-head l2norm (in place)
__global__ __launch_bounds__(256) void l2norm_qk(u16* __restrict__ Q, u16* __restrict__ K)
{
    u16* base = blockIdx.y ? K : Q;
    int w    = blockIdx.x * 4 + (threadIdx.x >> 6);   // row*4 + h
    int lane = threadIdx.x & 63;
    u16* p = base + (size_t)(w >> 2) * 1024 + (w & 3) * 256 + lane * 4;
    uint2 u = *(const uint2*)p;
    float f0 = bf2f(u.x), f1 = bf2f(u.x >> 16), f2 = bf2f(u.y), f3 = bf2f(u.y >> 16);
    float ss = f0 * f0 + f1 * f1 + f2 * f2 + f3 * f3;
#pragma unroll
    for (int m = 1; m < 64; m <<= 1) ss += __shfl_xor(ss, m);
    float inv = rsqrtf(ss + 1e-20f);
    uint2 o;
    o.x = (unsigned)f2bf(f0 * inv) | ((unsigned)f2bf(f1 * inv) << 16);
    o.y = (unsigned)f2bf(f2 * inv) | ((unsigned)f2bf(f3 * inv) << 16);
    *(uint2*)p = o;
}

// ---------------------------------------------------------------- Phase A (chunked WY precompute)
// Per (bh, chunk of 64): KK=K@K^T, QK=Q@K^T (MFMA), A = beta*stril(KK),
// T = (I+A)^{-1} via forward substitution, store T (hi/lo bf16) and
// QKt = tril_incl(QK) bf16. Layouts [t][t'] (t'-contiguous) for A-operand use.
#define AP 68
__global__ __launch_bounds__(256) void phaseA(
    const u16* __restrict__ Kb, const u16* __restrict__ Qb,
    const float* __restrict__ Bp,
    u16* __restrict__ Thi, u16* __restrict__ Tlo, u16* __restrict__ QKg)
{
    const int bh = blockIdx.x >> 4, ch = blockIdx.x & 15;
    const int bq = bh >> 2, h = bh & 3;
    const int tid = threadIdx.x;
    const int w = tid >> 6, L = tid & 63, fr = L & 15, fk = L >> 4;

    __shared__ u16 Ks[64 * 264];
    __shared__ u16 Qs[64 * 264];
    __shared__ float Af[64 * AP];
    __shared__ float Tf[64 * AP];
    __shared__ float bc[64];

    const size_t crow = ((size_t)bq * 1024 + ch * 64) * 1024 + (size_t)h * 256;
#pragma unroll
    for (int i = 0; i < 8; ++i) {
        int row = i * 8 + (tid >> 5), c8 = (tid & 31) * 8;
        uint4 kv = *(const uint4*)(Kb + crow + (size_t)row * 1024 + c8);
        uint4 qv = *(const uint4*)(Qb + crow + (size_t)row * 1024 + c8);
        *(uint4*)(Ks + row * 264 + c8) = kv;
        *(uint4*)(Qs + row * 264 + c8) = qv;
    }
    if (tid < 64) bc[tid] = Bp[(size_t)bh * 1024 + ch * 64 + tid];
    __syncthreads();

    f32x4 kk[4], qk[4];
#pragma unroll
    for (int n = 0; n < 4; ++n) { kk[n] = (f32x4){0,0,0,0}; qk[n] = (f32x4){0,0,0,0}; }
#pragma unroll
    for (int k0 = 0; k0 < 8; ++k0) {
        bf16x8 ak = *(const bf16x8*)(Ks + (w * 16 + fr) * 264 + k0 * 32 + fk * 8);
        bf16x8 aq = *(const bf16x8*)(Qs + (w * 16 + fr) * 264 + k0 * 32 + fk * 8);
#pragma unroll
        for (int n = 0; n < 4; ++n) {
            bf16x8 bk = *(const bf16x8*)(Ks + (n * 16 + fr) * 264 + k0 * 32 + fk * 8);
            kk[n] = MFMA16(ak, bk, kk[n], 0, 0, 0);
            qk[n] = MFMA16(aq, bk, qk[n], 0, 0, 0);
        }
    }
    const size_t obase = (size_t)(bh * 16 + ch) * 4096;
#pragma unroll
    for (int n = 0; n < 4; ++n)
#pragma unroll
        for (int j = 0; j < 4; ++j) {
            int t = w * 16 + fk * 4 + j, s = n * 16 + fr;
            Af[t * AP + s] = (s < t) ? bc[t] * kk[n][j] : 0.f;
            QKg[obase + t * 64 + s] = f2bf((s <= t) ? qk[n][j] : 0.f);
        }
    __syncthreads();

    // forward substitution: T[t][:] = e_t - sum_{s<t} A[t][s] T[s][:]
    {
        int j = w * 16 + fr;   // column owned by this lane group
        int p = fk;            // partial index 0..3
        for (int t = 0; t < 64; ++t) {
            float acc = 0.f;
            for (int s = p; s < t; s += 4) acc += Af[t * AP + s] * Tf[s * AP + j];
            acc += __shfl_xor(acc, 16);
            acc += __shfl_xor(acc, 32);
            float val = ((t == j) ? 1.f : 0.f) - acc;
            if (p == 0) Tf[t * AP + j] = val;
        }
    }
    __syncthreads();
#pragma unroll
    for (int e = 0; e < 16; ++e) {
        int idx = tid + e * 256;
        int t = idx >> 6, s = idx & 63;
        float f = Tf[t * AP + s];
        u16 hh = f2bf(f);
        Thi[obase + idx] = hh;
        Tlo[obase + idx] = f2bf(f - bf2f(hh));
    }
}

// ---------------------------------------------------------------- Phase B (chunked WY scan)
// 256 persistent blocks: bh = bid&31, dvb = bid>>5 (same-bh siblings share XCD).
// Per chunk: P=K@S0, O1=Q@S0 (S hi/lo bf16 in LDS), W=beta(V-P) -> W^T,
// E=T@W (T hi/lo from global), O=O1+QKt@E -> Vb in place, S += E^T@K (KT in LDS).
#define KTP 72
#define SHP 264
__global__ __launch_bounds__(256) void phaseB(
    const u16* __restrict__ Kb, const u16* __restrict__ Qb, u16* Vb,
    const float* __restrict__ Bp,
    const u16* __restrict__ Thi, const u16* __restrict__ Tlo, const u16* __restrict__ QKg)
{
    const int bh  = blockIdx.x & 31;
    const int dvb = blockIdx.x >> 5;
    const int bq = bh >> 2, h = bh & 3;
    const int tid = threadIdx.x;
    const int w = tid >> 6, L = tid & 63, fr = L & 15, fk = L >> 4;

    __shared__ u16 S_hi[32 * SHP];   // [dv][dk]
    __shared__ u16 S_lo[32 * SHP];
    __shared__ u16 KT[256 * KTP];    // [dk][t]
    __shared__ u16 W_T[32 * KTP];    // [dv][t]
    __shared__ u16 E_T[32 * KTP];
    __shared__ float bc[64];

    for (int i = tid; i < 32 * SHP; i += 256) { S_hi[i] = 0; S_lo[i] = 0; }
    __syncthreads();

    const size_t rb = ((size_t)bq * 1024) * 1024 + (size_t)h * 256;
    for (int c = 0; c < 16; ++c) {
        const size_t crow = rb + (size_t)(c * 64) * 1024;
        // (A) build KT (transposed K chunk) + stage beta
#pragma unroll
        for (int i = 0; i < 8; ++i) {
            int g = tid + i * 256;
            int t = g >> 5, d0 = (g & 31) * 8;
            union { uint4 q; u16 u[8]; } U;
            U.q = *(const uint4*)(Kb + crow + (size_t)t * 1024 + d0);
#pragma unroll
            for (int e = 0; e < 8; ++e) KT[(d0 + e) * KTP + t] = U.u[e];
        }
        if (tid < 64) bc[tid] = Bp[(size_t)bh * 1024 + c * 64 + tid];

        // (B) P = K@S0, O1 = Q@S0
        f32x4 accP[2], accO[2];
        accP[0] = accP[1] = accO[0] = accO[1] = (f32x4){0, 0, 0, 0};
        {
            const size_t arow = crow + (size_t)(w * 16 + fr) * 1024 + fk * 8;
#pragma unroll
            for (int k0 = 0; k0 < 8; ++k0) {
                bf16x8 kfr = *(const bf16x8*)(Kb + arow + k0 * 32);
                bf16x8 qfr = *(const bf16x8*)(Qb + arow + k0 * 32);
#pragma unroll
                for (int n = 0; n < 2; ++n) {
                    const u16* sp = S_hi + (n * 16 + fr) * SHP + k0 * 32 + fk * 8;
                    bf16x8 shi = *(const bf16x8*)sp;
                    bf16x8 slo = *(const bf16x8*)(S_lo + (n * 16 + fr) * SHP + k0 * 32 + fk * 8);
                    accP[n] = MFMA16(kfr, shi, accP[n], 0, 0, 0);
                    accP[n] = MFMA16(kfr, slo, accP[n], 0, 0, 0);
                    accO[n] = MFMA16(qfr, shi, accO[n], 0, 0, 0);
                    accO[n] = MFMA16(qfr, slo, accO[n], 0, 0, 0);
                }
            }
        }
        __syncthreads();   // KT + bc ready
        // (C) W = beta*(V - P) -> W_T
#pragma unroll
        for (int n = 0; n < 2; ++n)
#pragma unroll
            for (int j = 0; j < 4; ++j) {
                int t = w * 16 + fk * 4 + j, col = n * 16 + fr;
                float v = bf2f(Vb[crow + (size_t)t * 1024 + dvb * 32 + col]);
                W_T[col * KTP + t] = f2bf(bc[t] * (v - accP[n][j]));
            }
        __syncthreads();   // W_T ready
        // (D) E = T @ W
        f32x4 accE[2];
        accE[0] = accE[1] = (f32x4){0, 0, 0, 0};
        const size_t tbase = (size_t)(bh * 16 + c) * 4096 + (size_t)(w * 16 + fr) * 64 + fk * 8;
#pragma unroll
        for (int k0 = 0; k0 < 2; ++k0) {
            bf16x8 th = *(const bf16x8*)(Thi + tbase + k0 * 32);
            bf16x8 tl = *(const bf16x8*)(Tlo + tbase + k0 * 32);
#pragma unroll
            for (int n = 0; n < 2; ++n) {
                bf16x8 wf = *(const bf16x8*)(W_T + (n * 16 + fr) * KTP + k0 * 32 + fk * 8);
                accE[n] = MFMA16(th, wf, accE[n], 0, 0, 0);
                accE[n] = MFMA16(tl, wf, accE[n], 0, 0, 0);
            }
        }
#pragma unroll
        for (int n = 0; n < 2; ++n)
#pragma unroll
            for (int j = 0; j < 4; ++j) {
                int t = w * 16 + fk * 4 + j, col = n * 16 + fr;
                E_T[col * KTP + t] = f2bf(accE[n][j]);
            }
        __syncthreads();   // E_T ready
        // (E) O = O1 + QKt@E -> Vb
#pragma unroll
        for (int k0 = 0; k0 < 2; ++k0) {
            bf16x8 qk = *(const bf16x8*)(QKg + tbase + k0 * 32);
#pragma unroll
            for (int n = 0; n < 2; ++n) {
                bf16x8 ef = *(const bf16x8*)(E_T + (n * 16 + fr) * KTP + k0 * 32 + fk * 8);
                accO[n] = MFMA16(qk, ef, accO[n], 0, 0, 0);
            }
        }
#pragma unroll
        for (int n = 0; n < 2; ++n)
#pragma unroll
            for (int j = 0; j < 4; ++j) {
                int t = w * 16 + fk * 4 + j, col = n * 16 + fr;
                Vb[crow + (size_t)t * 1024 + dvb * 32 + col] = f2bf(accO[n][j]);
            }
        // (F) S += E^T @ K  (A = E_T [dv][t], B = KT [dk][t])
        {
            f32x4 dS[2][4];
#pragma unroll
            for (int m = 0; m < 2; ++m)
#pragma unroll
                for (int nn = 0; nn < 4; ++nn) dS[m][nn] = (f32x4){0, 0, 0, 0};
#pragma unroll
            for (int k0 = 0; k0 < 2; ++k0) {
                bf16x8 kf[4];
#pragma unroll
                for (int nn = 0; nn < 4; ++nn)
                    kf[nn] = *(const bf16x8*)(KT + (w * 64 + nn * 16 + fr) * KTP + k0 * 32 + fk * 8);
#pragma unroll
                for (int m = 0; m < 2; ++m) {
                    bf16x8 ef = *(const bf16x8*)(E_T + (m * 16 + fr) * KTP + k0 * 32 + fk * 8);
#pragma unroll
                    for (int nn = 0; nn < 4; ++nn)
                        dS[m][nn] = MFMA16(ef, kf[nn], dS[m][nn], 0, 0, 0);
                }
            }
#pragma unroll
            for (int m = 0; m < 2; ++m)
#pragma unroll
                for (int nn = 0; nn < 4; ++nn)
#pragma unroll
                    for (int j = 0; j < 4; ++j) {
                        int dvr = m * 16 + fk * 4 + j, dkc = w * 64 + nn * 16 + fr;
                        int idx = dvr * SHP + dkc;
                        float s = bf2f(S_hi[idx]) + bf2f(S_lo[idx]) + dS[m][nn][j];
                        u16 hh = f2bf(s);
                        S_hi[idx] = hh;
                        S_lo[idx] = f2bf(s - bf2f(hh));
                    }
        }
        __syncthreads();   // S updated; buffers reusable
    }
}

// ---------------------------------------------------------------- RMSNorm over Dv, in place
__global__ __launch_bounds__(256) void rmsnorm_o(u16* V, const u16* __restrict__ gn)
{
    int w    = blockIdx.x * 4 + (threadIdx.x >> 6);   // (b*1024+t)*4 + h
    int lane = threadIdx.x & 63;
    u16* p = V + (size_t)(w >> 2) * 1024 + (w & 3) * 256 + lane * 4;
    uint2 u = *(const uint2*)p;
    float f0 = bf2f(u.x), f1 = bf2f(u.x >> 16), f2 = bf2f(u.y), f3 = bf2f(u.y >> 16);
    float ss = f0 * f0 + f1 * f1 + f2 * f2 + f3 * f3;
#pragma unroll
    for (int m = 1; m < 64; m <<= 1) ss += __shfl_xor(ss, m);
    float sc = rsqrtf(ss * (1.0f / 256.0f) + 1e-5f);
    int d0 = lane * 4;
    uint2 gu = *(const uint2*)(gn + d0);
    float g0 = bf2f(gu.x), g1 = bf2f(gu.x >> 16), g2 = bf2f(gu.y), g3 = bf2f(gu.y >> 16);
    uint2 o;
    o.x = (unsigned)f2bf(f0 * sc * g0) | ((unsigned)f2bf(f1 * sc * g1) << 16);
    o.y = (unsigned)f2bf(f2 * sc * g2) | ((unsigned)f2bf(f3 * sc * g3) << 16);
    *(uint2*)p = o;
}

// ---------------------------------------------------------------- launch
extern "C" void kernel_launch(void* const* d_in, const int* in_sizes, int n_in,
                              void* d_out, int out_size, void* d_ws, size_t ws_size,
                              hipStream_t stream)
{
    const void* x  = d_in[0];
    const void* Wq = d_in[1];
    const void* Wk = d_in[2];
    const void* Wv = d_in[3];
    const void* Wb = d_in[4];
    const void* Wo = d_in[5];
    const void* gn = d_in[6];

    char* ws = (char*)d_ws;
    const size_t OFF_FLAG = 0;                        // 4 KB block
    const size_t OFF_WBC  = 4096;                     // 8 KB (Wbeta bf16)
    const size_t OFF_GNC  = OFF_WBC + 8192;           // 4 KB (g_norm bf16)
    const size_t OFF_XB   = OFF_GNC + 4096;           // 16 MB (x bf16; reused by T/QKt after projections)
    const size_t OFF_WQT  = OFF_XB + 16777216;        // 2 MB
    const size_t OFF_WKT  = OFF_WQT + 2097152;        // 2 MB
    const size_t OFF_WVT  = OFF_WKT + 2097152;        // 2 MB
    const size_t OFF_WOT  = OFF_WVT + 2097152;        // 2 MB
    const size_t OFF_Q    = OFF_WOT + 2097152;        // 16 MB
    const size_t OFF_K    = OFF_Q + 16777216;         // 16 MB
    const size_t OFF_V    = OFF_K + 16777216;         // 16 MB
    const size_t OFF_BP   = OFF_V + 16777216;         // 128 KB  -> ~72.6 MB total

    // T/QKt overlay inside the (dead-after-projections) Xb region
    const size_t OFF_THI  = OFF_XB;                   // 4.19 MB
    const size_t OFF_TLO  = OFF_XB + 4194304;         // 4.19 MB
    const size_t OFF_QKT  = OFF_XB + 8388608;         // 4.19 MB

    int*   flag = (int*)(ws + OFF_FLAG);
    u16*   Wbc  = (u16*)(ws + OFF_WBC);
    u16*   gnc  = (u16*)(ws + OFF_GNC);
    u16*   Xb   = (u16*)(ws + OFF_XB);
    u16*   wqT  = (u16*)(ws + OFF_WQT);
    u16*   wkT  = (u16*)(ws + OFF_WKT);
    u16*   wvT  = (u16*)(ws + OFF_WVT);
    u16*   woT  = (u16*)(ws + OFF_WOT);
    u16*   Qb   = (u16*)(ws + OFF_Q);
    u16*   Kb   = (u16*)(ws + OFF_K);
    u16*   Vb   = (u16*)(ws + OFF_V);
    float* Bp   = (float*)(ws + OFF_BP);
    u16*   Thi  = (u16*)(ws + OFF_THI);
    u16*   Tlo  = (u16*)(ws + OFF_TLO);
    u16*   QKg  = (u16*)(ws + OFF_QKT);

    detect_dtype<<<1, 64, 0, stream>>>((const unsigned*)Wq, flag);
    convert_vec<<<2048, 256, 0, stream>>>(x, Xb, 8388608, flag);
    convert_vec<<<16, 256, 0, stream>>>(Wb, Wbc, 4096, flag);
    convert_vec<<<1, 256, 0, stream>>>(gn, gnc, 256, flag);
    transpose_cvt<<<dim3(16, 32, 4), 256, 0, stream>>>(Wq, Wk, Wv, Wo, wqT, wkT, wvT, woT, flag);

    gemm_bt<<<dim3(64, 8), 256, 0, stream>>>(Xb, wqT, Qb, 8192, 1024, 1024, flag, 0);
    gemm_bt<<<dim3(64, 8), 256, 0, stream>>>(Xb, wkT, Kb, 8192, 1024, 1024, flag, 0);
    gemm_bt<<<dim3(64, 8), 256, 0, stream>>>(Xb, wvT, Vb, 8192, 1024, 1024, flag, 0);
    beta_kernel<<<2048, 256, 0, stream>>>(Xb, Wbc, Bp);
    l2norm_qk<<<dim3(8192, 2), 256, 0, stream>>>(Qb, Kb);

    phaseA<<<512, 256, 0, stream>>>(Kb, Qb, Bp, Thi, Tlo, QKg);
    phaseB<<<256, 256, 0, stream>>>(Kb, Qb, Vb, Bp, Thi, Tlo, QKg);

    rmsnorm_o<<<8192, 256, 0, stream>>>(Vb, gnc);
    gemm_bt<<<dim3(64, 8), 256, 0, stream>>>(Vb, woT, d_out, 8192, 1024, 1024, flag, 1);
}

// Round 6
// 363.113 us; speedup vs baseline: 1.7911x; 1.2107x over previous
//
#include <hip/hip_runtime.h>
#include <hip/hip_bf16.h>
#include <math.h>

typedef unsigned short u16;
typedef __attribute__((ext_vector_type(8))) __bf16 bf16x8;
typedef __attribute__((ext_vector_type(4))) float f32x4;

#define MFMA16 __builtin_amdgcn_mfma_f32_16x16x32_bf16

__device__ __forceinline__ float bf2f(unsigned int u) {
    union { unsigned int i; float f; } x;
    x.i = (u & 0xffffu) << 16;
    return x.f;
}
__device__ __forceinline__ u16 f2bf(float f) {
    unsigned int i = __float_as_uint(f);
    unsigned int r = (i + 0x7fffu + ((i >> 16) & 1u)) >> 16;
    return (u16)r;
}

__device__ __forceinline__ void gload_lds16(const void* g, void* l) {
    __builtin_amdgcn_global_load_lds((const __attribute__((address_space(1))) void*)g,
                                     (__attribute__((address_space(3))) void*)l, 16, 0, 0);
}

// ---------------------------------------------------------------- dtype detect
__global__ void detect_dtype(const unsigned* __restrict__ wq, int* __restrict__ flag)
{
    int lane = threadIdx.x;   // 64 threads
    unsigned lo = wq[lane] & 0xffffu;
    unsigned e = (lo >> 7) & 0xffu;
    int m = (e >= 0x6e && e <= 0x7e) ? 1 : 0;
#pragma unroll
    for (int s = 1; s < 64; s <<= 1) m += __shfl_xor(m, s);
    if (lane == 0) flag[0] = (m >= 32) ? 0 : 1;
}

// ---------------------------------------------------------------- convert (elementwise)
__global__ __launch_bounds__(256) void convert_vec(
    const void* __restrict__ src, u16* __restrict__ dst, int n, const int* __restrict__ flag)
{
    int stride = gridDim.x * 256;
    int i0 = blockIdx.x * 256 + threadIdx.x;
    if (*flag) {
        const float* s = (const float*)src;
        for (int i = i0; i < n; i += stride) dst[i] = f2bf(s[i]);
    } else {
        const u16* s = (const u16*)src;
        for (int i = i0; i < n; i += stride) dst[i] = s[i];
    }
}

// ---------------------------------------------------------------- transpose+convert
__global__ __launch_bounds__(256) void transpose_cvt(
    const void* __restrict__ w0, const void* __restrict__ w1,
    const void* __restrict__ w2, const void* __restrict__ w3,
    u16* __restrict__ o0, u16* __restrict__ o1,
    u16* __restrict__ o2, u16* __restrict__ o3, const int* __restrict__ flag)
{
    const void* in; u16* out;
    switch (blockIdx.z) {
        case 0: in = w0; out = o0; break;
        case 1: in = w1; out = o1; break;
        case 2: in = w2; out = o2; break;
        default: in = w3; out = o3; break;
    }
    int n  = blockIdx.x * 64 + (threadIdx.x & 63);
    int kb = blockIdx.y * 32 + (threadIdx.x >> 6) * 8;
    u16 v[8];
    if (*flag) {
        const float* f = (const float*)in;
#pragma unroll
        for (int j = 0; j < 8; ++j) v[j] = f2bf(f[(size_t)(kb + j) * 1024 + n]);
    } else {
        const u16* s = (const u16*)in;
#pragma unroll
        for (int j = 0; j < 8; ++j) v[j] = s[(size_t)(kb + j) * 1024 + n];
    }
    uint4 pk;
    pk.x = (unsigned)v[0] | ((unsigned)v[1] << 16);
    pk.y = (unsigned)v[2] | ((unsigned)v[3] << 16);
    pk.z = (unsigned)v[4] | ((unsigned)v[5] << 16);
    pk.w = (unsigned)v[6] | ((unsigned)v[7] << 16);
    *(uint4*)(out + (size_t)n * 1024 + kb) = pk;
}

// ---------------------------------------------------------------- GEMM (m97-style)
__global__ __launch_bounds__(256) void gemm_bt(
    const u16* __restrict__ A, const u16* __restrict__ BT, void* __restrict__ C,
    int M, int Nn, int K, const int* __restrict__ flag, int fp32_out)
{
    __shared__ alignas(16) u16 As[128 * 32];
    __shared__ alignas(16) u16 Bs[128 * 32];
    const int tid  = threadIdx.x;
    const int lane = tid & 63;
    const int wv   = tid >> 6;
    const int wm   = wv >> 1, wn = wv & 1;
    const int bm   = blockIdx.x * 128, bn = blockIdx.y * 128;
    const int fr   = lane & 15, fk = lane >> 4;

    f32x4 acc[4][4];
#pragma unroll
    for (int i = 0; i < 4; ++i)
#pragma unroll
        for (int j = 0; j < 4; ++j) acc[i][j] = (f32x4){0.f, 0.f, 0.f, 0.f};

    for (int k0 = 0; k0 < K; k0 += 32) {
        __syncthreads();
#pragma unroll
        for (int p = 0; p < 2; ++p) {
            int i = tid + p * 256;
            int r = i >> 2, kc = (i & 3) << 3;
            gload_lds16(A  + (size_t)(bm + r) * K + k0 + kc,
                        (char*)As + (size_t)(wv * 64 + p * 256) * 16);
            gload_lds16(BT + (size_t)(bn + r) * K + k0 + kc,
                        (char*)Bs + (size_t)(wv * 64 + p * 256) * 16);
        }
        __syncthreads();
        bf16x8 af[4], bfr[4];
#pragma unroll
        for (int mi = 0; mi < 4; ++mi)
            af[mi] = *(const bf16x8*)(As + (wm * 64 + mi * 16 + fr) * 32 + fk * 8);
#pragma unroll
        for (int ni = 0; ni < 4; ++ni)
            bfr[ni] = *(const bf16x8*)(Bs + (wn * 64 + ni * 16 + fr) * 32 + fk * 8);
#pragma unroll
        for (int mi = 0; mi < 4; ++mi)
#pragma unroll
            for (int ni = 0; ni < 4; ++ni)
                acc[mi][ni] = MFMA16(af[mi], bfr[ni], acc[mi][ni], 0, 0, 0);
    }
    bool f32st = fp32_out && (*flag);
    if (f32st) {
        float* Cf = (float*)C;
#pragma unroll
        for (int mi = 0; mi < 4; ++mi)
#pragma unroll
            for (int ni = 0; ni < 4; ++ni)
#pragma unroll
                for (int j = 0; j < 4; ++j) {
                    int row = bm + wm * 64 + mi * 16 + fk * 4 + j;
                    int col = bn + wn * 64 + ni * 16 + fr;
                    Cf[(size_t)row * Nn + col] = acc[mi][ni][j];
                }
    } else {
        u16* Cb = (u16*)C;
#pragma unroll
        for (int mi = 0; mi < 4; ++mi)
#pragma unroll
            for (int ni = 0; ni < 4; ++ni)
#pragma unroll
                for (int j = 0; j < 4; ++j) {
                    int row = bm + wm * 64 + mi * 16 + fk * 4 + j;
                    int col = bn + wn * 64 + ni * 16 + fr;
                    Cb[(size_t)row * Nn + col] = f2bf(acc[mi][ni][j]);
                }
    }
}

// ---------------------------------------------------------------- beta = sigmoid(x @ Wbeta)
__global__ __launch_bounds__(256) void beta_kernel(
    const u16* __restrict__ x, const u16* __restrict__ Wb, float* __restrict__ beta)
{
    int row  = blockIdx.x * 4 + (threadIdx.x >> 6);
    int lane = threadIdx.x & 63;
    const u16* xr = x + (size_t)row * 1024;
    float a0 = 0.f, a1 = 0.f, a2 = 0.f, a3 = 0.f;
    for (int c = 0; c < 16; ++c) {
        int k = c * 64 + lane;
        float xv = bf2f(xr[k]);
        uint2 w = *(const uint2*)(Wb + (size_t)k * 4);
        a0 += xv * bf2f(w.x);
        a1 += xv * bf2f(w.x >> 16);
        a2 += xv * bf2f(w.y);
        a3 += xv * bf2f(w.y >> 16);
    }
#pragma unroll
    for (int m = 1; m < 64; m <<= 1) {
        a0 += __shfl_xor(a0, m); a1 += __shfl_xor(a1, m);
        a2 += __shfl_xor(a2, m); a3 += __shfl_xor(a3, m);
    }
    if (lane == 0) {
        int b = row >> 10, nn = row & 1023;
        beta[(size_t)(b * 4 + 0) * 1024 + nn] = 1.f / (1.f + expf(-a0));
        beta[(size_t)(b * 4 + 1) * 1024 + nn] = 1.f / (1.f + expf(-a1));
        beta[(size_t)(b * 4 + 2) * 1024 + nn] = 1.f / (1.f + expf(-a2));
        beta[(size_t)(b * 4 + 3) * 1024 + nn] = 1.f / (1.f + expf(-a3));
    }
}

// ---------------------------------------------------------------- per-head l2norm (in place)
__global__ __launch_bounds__(256) void l2norm_qk(u16* __restrict__ Q, u16* __restrict__ K)
{
    u16* base = blockIdx.y ? K : Q;
    int w    = blockIdx.x * 4 + (threadIdx.x >> 6);   // row*4 + h
    int lane = threadIdx.x & 63;
    u16* p = base + (size_t)(w >> 2) * 1024 + (w & 3) * 256 + lane * 4;
    uint2 u = *(const uint2*)p;
    float f0 = bf2f(u.x), f1 = bf2f(u.x >> 16), f2 = bf2f(u.y), f3 = bf2f(u.y >> 16);
    float ss = f0 * f0 + f1 * f1 + f2 * f2 + f3 * f3;
#pragma unroll
    for (int m = 1; m < 64; m <<= 1) ss += __shfl_xor(ss, m);
    float inv = rsqrtf(ss + 1e-20f);
    uint2 o;
    o.x = (unsigned)f2bf(f0 * inv) | ((unsigned)f2bf(f1 * inv) << 16);
    o.y = (unsigned)f2bf(f2 * inv) | ((unsigned)f2bf(f3 * inv) << 16);
    *(uint2*)p = o;
}

// ---------------------------------------------------------------- Phase A (chunked WY precompute)
// Per (bh, chunk of 64): KK=K@K^T, QK=Q@K^T (MFMA), A = beta*stril(KK),
// T = (I+A)^{-1} forward substitution -> Thi/Tlo (hi/lo bf16),
// QKt = tril_incl(QK) bf16, and K^T chunk -> KTg [bh*16+ch][dk=256][t=64].
#define AP 68
__global__ __launch_bounds__(256) void phaseA(
    const u16* __restrict__ Kb, const u16* __restrict__ Qb,
    const float* __restrict__ Bp,
    u16* __restrict__ Thi, u16* __restrict__ Tlo, u16* __restrict__ QKg,
    u16* __restrict__ KTg)
{
    const int bh = blockIdx.x >> 4, ch = blockIdx.x & 15;
    const int bq = bh >> 2, h = bh & 3;
    const int tid = threadIdx.x;
    const int w = tid >> 6, L = tid & 63, fr = L & 15, fk = L >> 4;

    __shared__ u16 Ks[64 * 264];
    __shared__ u16 Qs[64 * 264];
    __shared__ float Af[64 * AP];
    __shared__ float Tf[64 * AP];
    __shared__ float bc[64];

    const size_t crow = ((size_t)bq * 1024 + ch * 64) * 1024 + (size_t)h * 256;
#pragma unroll
    for (int i = 0; i < 8; ++i) {
        int row = i * 8 + (tid >> 5), c8 = (tid & 31) * 8;
        uint4 kv = *(const uint4*)(Kb + crow + (size_t)row * 1024 + c8);
        uint4 qv = *(const uint4*)(Qb + crow + (size_t)row * 1024 + c8);
        *(uint4*)(Ks + row * 264 + c8) = kv;
        *(uint4*)(Qs + row * 264 + c8) = qv;
    }
    if (tid < 64) bc[tid] = Bp[(size_t)bh * 1024 + ch * 64 + tid];
    __syncthreads();

    // K^T chunk -> global (coalesced 128B runs; replaces phaseB's 32-way LDS scatter)
    const size_t kbase = (size_t)(bh * 16 + ch) * 16384;
#pragma unroll
    for (int i = 0; i < 8; ++i) {
        int item = tid + i * 256;
        int t = item & 63, g = item >> 6;        // g: dk-group of 8
        union { uint4 q; u16 u[8]; } U;
        U.q = *(const uint4*)(Ks + t * 264 + g * 8);
#pragma unroll
        for (int e = 0; e < 8; ++e)
            KTg[kbase + (size_t)(g * 8 + e) * 64 + t] = U.u[e];
    }

    f32x4 kk[4], qk[4];
#pragma unroll
    for (int n = 0; n < 4; ++n) { kk[n] = (f32x4){0,0,0,0}; qk[n] = (f32x4){0,0,0,0}; }
#pragma unroll
    for (int k0 = 0; k0 < 8; ++k0) {
        bf16x8 ak = *(const bf16x8*)(Ks + (w * 16 + fr) * 264 + k0 * 32 + fk * 8);
        bf16x8 aq = *(const bf16x8*)(Qs + (w * 16 + fr) * 264 + k0 * 32 + fk * 8);
#pragma unroll
        for (int n = 0; n < 4; ++n) {
            bf16x8 bk = *(const bf16x8*)(Ks + (n * 16 + fr) * 264 + k0 * 32 + fk * 8);
            kk[n] = MFMA16(ak, bk, kk[n], 0, 0, 0);
            qk[n] = MFMA16(aq, bk, qk[n], 0, 0, 0);
        }
    }
    const size_t obase = (size_t)(bh * 16 + ch) * 4096;
#pragma unroll
    for (int n = 0; n < 4; ++n)
#pragma unroll
        for (int j = 0; j < 4; ++j) {
            int t = w * 16 + fk * 4 + j, s = n * 16 + fr;
            Af[t * AP + s] = (s < t) ? bc[t] * kk[n][j] : 0.f;
            QKg[obase + t * 64 + s] = f2bf((s <= t) ? qk[n][j] : 0.f);
        }
    __syncthreads();

    // forward substitution: T[t][:] = e_t - sum_{s<t} A[t][s] T[s][:]
    {
        int j = w * 16 + fr;   // column owned by this lane group
        int p = fk;            // partial index 0..3
        for (int t = 0; t < 64; ++t) {
            float acc = 0.f;
            for (int s = p; s < t; s += 4) acc += Af[t * AP + s] * Tf[s * AP + j];
            acc += __shfl_xor(acc, 16);
            acc += __shfl_xor(acc, 32);
            float val = ((t == j) ? 1.f : 0.f) - acc;
            if (p == 0) Tf[t * AP + j] = val;
        }
    }
    __syncthreads();
#pragma unroll
    for (int e = 0; e < 16; ++e) {
        int idx = tid + e * 256;
        int t = idx >> 6, s = idx & 63;
        float f = Tf[t * AP + s];
        u16 hh = f2bf(f);
        Thi[obase + idx] = hh;
        Tlo[obase + idx] = f2bf(f - bf2f(hh));
    }
}

// ---------------------------------------------------------------- Phase B (chunked WY scan)
// 512 blocks: bh = bid&31, dvb = bid>>5 (0..15, dv-slice of 16). 4 waves.
// Per chunk: prefetch T/QKt/KT/V (global, chunk-indexed) -> regs;
// (B) P=K@S0, O1=Q@S0 (S hi/lo bf16 LDS); (C) W^T=beta(V-P); sync;
// (D) E=T@W -> E_T; sync; (E) O=O1+QKt@E -> Vb; (F) S+=E^T@K (KTg); sync.
#define KTP 72
#define SHP 264
__global__ __launch_bounds__(256) void phaseB(
    const u16* __restrict__ Kb, const u16* __restrict__ Qb, u16* Vb,
    const float* __restrict__ Bp,
    const u16* __restrict__ Thi, const u16* __restrict__ Tlo,
    const u16* __restrict__ QKg, const u16* __restrict__ KTg)
{
    const int bh  = blockIdx.x & 31;
    const int dvb = blockIdx.x >> 5;      // 0..15
    const int bq = bh >> 2, h = bh & 3;
    const int tid = threadIdx.x;
    const int w = tid >> 6, L = tid & 63, fr = L & 15, fk = L >> 4;

    __shared__ u16 S_hi[16 * SHP];   // [dv][dk] (stores S^T slice)
    __shared__ u16 S_lo[16 * SHP];
    __shared__ u16 W_T[16 * KTP];    // [dv][t]
    __shared__ u16 E_T[16 * KTP];
    __shared__ float bc[1024];

    for (int i = tid; i < 16 * SHP; i += 256) { S_hi[i] = 0; S_lo[i] = 0; }
    for (int i = tid; i < 1024; i += 256) bc[i] = Bp[(size_t)bh * 1024 + i];
    __syncthreads();

    const size_t rb = ((size_t)bq * 1024) * 1024 + (size_t)h * 256;
    for (int c = 0; c < 16; ++c) {
        const size_t crow = rb + (size_t)(c * 64) * 1024;
        const size_t tbase = (size_t)(bh * 16 + c) * 4096 + (size_t)(w * 16 + fr) * 64 + fk * 8;
        const size_t kbase = (size_t)(bh * 16 + c) * 16384;

        // -------- prefetch all chunk-indexed global data (T14: issue early)
        bf16x8 th[2], tl[2], qk2[2], kf[2][4];
        u16 vr[4];
#pragma unroll
        for (int k0 = 0; k0 < 2; ++k0) {
            th[k0]  = *(const bf16x8*)(Thi + tbase + k0 * 32);
            tl[k0]  = *(const bf16x8*)(Tlo + tbase + k0 * 32);
            qk2[k0] = *(const bf16x8*)(QKg + tbase + k0 * 32);
#pragma unroll
            for (int nn = 0; nn < 4; ++nn)
                kf[k0][nn] = *(const bf16x8*)(KTg + kbase
                              + (size_t)(w * 64 + nn * 16 + fr) * 64 + k0 * 32 + fk * 8);
        }
#pragma unroll
        for (int j = 0; j < 4; ++j)
            vr[j] = Vb[crow + (size_t)(w * 16 + fk * 4 + j) * 1024 + dvb * 16 + fr];

        // -------- (B) P = K@S0, O1 = Q@S0 (A rows t=w*16+fr; B rows dv=fr)
        f32x4 accP = (f32x4){0,0,0,0}, accO = (f32x4){0,0,0,0};
        const size_t arow = crow + (size_t)(w * 16 + fr) * 1024 + fk * 8;
#pragma unroll
        for (int k0 = 0; k0 < 8; ++k0) {
            bf16x8 kfr = *(const bf16x8*)(Kb + arow + k0 * 32);
            bf16x8 qfr = *(const bf16x8*)(Qb + arow + k0 * 32);
            bf16x8 shi = *(const bf16x8*)(S_hi + fr * SHP + k0 * 32 + fk * 8);
            bf16x8 slo = *(const bf16x8*)(S_lo + fr * SHP + k0 * 32 + fk * 8);
            accP = MFMA16(kfr, shi, accP, 0, 0, 0);
            accP = MFMA16(kfr, slo, accP, 0, 0, 0);
            accO = MFMA16(qfr, shi, accO, 0, 0, 0);
            accO = MFMA16(qfr, slo, accO, 0, 0, 0);
        }
        // -------- (C) W^T = beta*(V - P)
#pragma unroll
        for (int j = 0; j < 4; ++j) {
            int t = w * 16 + fk * 4 + j;
            W_T[fr * KTP + t] = f2bf(bc[c * 64 + t] * (bf2f(vr[j]) - accP[j]));
        }
        __syncthreads();          // W_T ready
        // -------- (D) E = T @ W
        f32x4 accE = (f32x4){0,0,0,0};
#pragma unroll
        for (int k0 = 0; k0 < 2; ++k0) {
            bf16x8 wf = *(const bf16x8*)(W_T + fr * KTP + k0 * 32 + fk * 8);
            accE = MFMA16(th[k0], wf, accE, 0, 0, 0);
            accE = MFMA16(tl[k0], wf, accE, 0, 0, 0);
        }
#pragma unroll
        for (int j = 0; j < 4; ++j)
            E_T[fr * KTP + (w * 16 + fk * 4 + j)] = f2bf(accE[j]);
        __syncthreads();          // E_T ready
        // -------- (E) O = O1 + QKt @ E -> Vb
        bf16x8 ef[2];
#pragma unroll
        for (int k0 = 0; k0 < 2; ++k0) {
            ef[k0] = *(const bf16x8*)(E_T + fr * KTP + k0 * 32 + fk * 8);
            accO = MFMA16(qk2[k0], ef[k0], accO, 0, 0, 0);
        }
#pragma unroll
        for (int j = 0; j < 4; ++j)
            Vb[crow + (size_t)(w * 16 + fk * 4 + j) * 1024 + dvb * 16 + fr] = f2bf(accO[j]);
        // -------- (F) S += E^T @ K (A=E_T rows dv=fr; B=KTg rows dk)
        f32x4 dS[4];
#pragma unroll
        for (int nn = 0; nn < 4; ++nn) dS[nn] = (f32x4){0,0,0,0};
#pragma unroll
        for (int k0 = 0; k0 < 2; ++k0)
#pragma unroll
            for (int nn = 0; nn < 4; ++nn)
                dS[nn] = MFMA16(ef[k0], kf[k0][nn], dS[nn], 0, 0, 0);
#pragma unroll
        for (int nn = 0; nn < 4; ++nn)
#pragma unroll
            for (int j = 0; j < 4; ++j) {
                int dvr = fk * 4 + j, dkc = w * 64 + nn * 16 + fr;
                int idx = dvr * SHP + dkc;
                float s = bf2f(S_hi[idx]) + bf2f(S_lo[idx]) + dS[nn][j];
                u16 hh = f2bf(s);
                S_hi[idx] = hh;
                S_lo[idx] = f2bf(s - bf2f(hh));
            }
        __syncthreads();          // S ready for next chunk
    }
}

// ---------------------------------------------------------------- RMSNorm over Dv, in place
__global__ __launch_bounds__(256) void rmsnorm_o(u16* V, const u16* __restrict__ gn)
{
    int w    = blockIdx.x * 4 + (threadIdx.x >> 6);   // (b*1024+t)*4 + h
    int lane = threadIdx.x & 63;
    u16* p = V + (size_t)(w >> 2) * 1024 + (w & 3) * 256 + lane * 4;
    uint2 u = *(const uint2*)p;
    float f0 = bf2f(u.x), f1 = bf2f(u.x >> 16), f2 = bf2f(u.y), f3 = bf2f(u.y >> 16);
    float ss = f0 * f0 + f1 * f1 + f2 * f2 + f3 * f3;
#pragma unroll
    for (int m = 1; m < 64; m <<= 1) ss += __shfl_xor(ss, m);
    float sc = rsqrtf(ss * (1.0f / 256.0f) + 1e-5f);
    int d0 = lane * 4;
    uint2 gu = *(const uint2*)(gn + d0);
    float g0 = bf2f(gu.x), g1 = bf2f(gu.x >> 16), g2 = bf2f(gu.y), g3 = bf2f(gu.y >> 16);
    uint2 o;
    o.x = (unsigned)f2bf(f0 * sc * g0) | ((unsigned)f2bf(f1 * sc * g1) << 16);
    o.y = (unsigned)f2bf(f2 * sc * g2) | ((unsigned)f2bf(f3 * sc * g3) << 16);
    *(uint2*)p = o;
}

// ---------------------------------------------------------------- launch
extern "C" void kernel_launch(void* const* d_in, const int* in_sizes, int n_in,
                              void* d_out, int out_size, void* d_ws, size_t ws_size,
                              hipStream_t stream)
{
    const void* x  = d_in[0];
    const void* Wq = d_in[1];
    const void* Wk = d_in[2];
    const void* Wv = d_in[3];
    const void* Wb = d_in[4];
    const void* Wo = d_in[5];
    const void* gn = d_in[6];

    char* ws = (char*)d_ws;
    const size_t OFF_FLAG = 0;                        // 4 KB block
    const size_t OFF_WBC  = 4096;                     // 8 KB (Wbeta bf16)
    const size_t OFF_GNC  = OFF_WBC + 8192;           // 4 KB (g_norm bf16)
    const size_t OFF_XB   = OFF_GNC + 4096;           // 16 MB (x bf16; reused by T/QKt after projections)
    const size_t OFF_WQT  = OFF_XB + 16777216;        // 2 MB
    const size_t OFF_WKT  = OFF_WQT + 2097152;        // 2 MB
    const size_t OFF_WVT  = OFF_WKT + 2097152;        // 2 MB
    const size_t OFF_WOT  = OFF_WVT + 2097152;        // 2 MB
    const size_t OFF_Q    = OFF_WOT + 2097152;        // 16 MB
    const size_t OFF_K    = OFF_Q + 16777216;         // 16 MB
    const size_t OFF_V    = OFF_K + 16777216;         // 16 MB
    const size_t OFF_BP   = OFF_V + 16777216;         // 128 KB  -> ~72.6 MB total

    // T/QKt overlay inside the (dead-after-projections) Xb region
    const size_t OFF_THI  = OFF_XB;                   // 4.19 MB
    const size_t OFF_TLO  = OFF_XB + 4194304;         // 4.19 MB
    const size_t OFF_QKT  = OFF_XB + 8388608;         // 4.19 MB

    int*   flag = (int*)(ws + OFF_FLAG);
    u16*   Wbc  = (u16*)(ws + OFF_WBC);
    u16*   gnc  = (u16*)(ws + OFF_GNC);
    u16*   Xb   = (u16*)(ws + OFF_XB);
    u16*   wqT  = (u16*)(ws + OFF_WQT);
    u16*   wkT  = (u16*)(ws + OFF_WKT);
    u16*   wvT  = (u16*)(ws + OFF_WVT);
    u16*   woT  = (u16*)(ws + OFF_WOT);
    u16*   Qb   = (u16*)(ws + OFF_Q);
    u16*   Kb   = (u16*)(ws + OFF_K);
    u16*   Vb   = (u16*)(ws + OFF_V);
    float* Bp   = (float*)(ws + OFF_BP);
    u16*   Thi  = (u16*)(ws + OFF_THI);
    u16*   Tlo  = (u16*)(ws + OFF_TLO);
    u16*   QKg  = (u16*)(ws + OFF_QKT);
    // KTg (16 MB exactly) lives in d_out: dead until final GEMM overwrites it.
    u16*   KTg  = (u16*)d_out;

    detect_dtype<<<1, 64, 0, stream>>>((const unsigned*)Wq, flag);
    convert_vec<<<2048, 256, 0, stream>>>(x, Xb, 8388608, flag);
    convert_vec<<<16, 256, 0, stream>>>(Wb, Wbc, 4096, flag);
    convert_vec<<<1, 256, 0, stream>>>(gn, gnc, 256, flag);
    transpose_cvt<<<dim3(16, 32, 4), 256, 0, stream>>>(Wq, Wk, Wv, Wo, wqT, wkT, wvT, woT, flag);

    gemm_bt<<<dim3(64, 8), 256, 0, stream>>>(Xb, wqT, Qb, 8192, 1024, 1024, flag, 0);
    gemm_bt<<<dim3(64, 8), 256, 0, stream>>>(Xb, wkT, Kb, 8192, 1024, 1024, flag, 0);
    gemm_bt<<<dim3(64, 8), 256, 0, stream>>>(Xb, wvT, Vb, 8192, 1024, 1024, flag, 0);
    beta_kernel<<<2048, 256, 0, stream>>>(Xb, Wbc, Bp);
    l2norm_qk<<<dim3(8192, 2), 256, 0, stream>>>(Qb, Kb);

    phaseA<<<512, 256, 0, stream>>>(Kb, Qb, Bp, Thi, Tlo, QKg, KTg);
    phaseB<<<512, 256, 0, stream>>>(Kb, Qb, Vb, Bp, Thi, Tlo, QKg, KTg);

    rmsnorm_o<<<8192, 256, 0, stream>>>(Vb, gnc);
    gemm_bt<<<dim3(64, 8), 256, 0, stream>>>(Vb, woT, d_out, 8192, 1024, 1024, flag, 1);
}

// Round 7
// 336.658 us; speedup vs baseline: 1.9318x; 1.0786x over previous
//
#include <hip/hip_runtime.h>
#include <hip/hip_bf16.h>
#include <math.h>

typedef unsigned short u16;
typedef __attribute__((ext_vector_type(8))) __bf16 bf16x8;
typedef __attribute__((ext_vector_type(4))) float f32x4;

#define MFMA16 __builtin_amdgcn_mfma_f32_16x16x32_bf16

__device__ __forceinline__ float bf2f(unsigned int u) {
    union { unsigned int i; float f; } x;
    x.i = (u & 0xffffu) << 16;
    return x.f;
}
__device__ __forceinline__ u16 f2bf(float f) {
    unsigned int i = __float_as_uint(f);
    unsigned int r = (i + 0x7fffu + ((i >> 16) & 1u)) >> 16;
    return (u16)r;
}

__device__ __forceinline__ void gload_lds16(const void* g, void* l) {
    __builtin_amdgcn_global_load_lds((const __attribute__((address_space(1))) void*)g,
                                     (__attribute__((address_space(3))) void*)l, 16, 0, 0);
}

// lgkm-only barrier: LDS producer/consumer sync WITHOUT draining global loads
// (compiler's __syncthreads emits vmcnt(0) too — that was phaseB's 80% stall).
#define BARS() do { asm volatile("s_waitcnt lgkmcnt(0)" ::: "memory"); \
                    __builtin_amdgcn_s_barrier(); } while (0)

// ---------------------------------------------------------------- dtype detect
__global__ void detect_dtype(const unsigned* __restrict__ wq, int* __restrict__ flag)
{
    int lane = threadIdx.x;   // 64 threads
    unsigned lo = wq[lane] & 0xffffu;
    unsigned e = (lo >> 7) & 0xffu;
    int m = (e >= 0x6e && e <= 0x7e) ? 1 : 0;
#pragma unroll
    for (int s = 1; s < 64; s <<= 1) m += __shfl_xor(m, s);
    if (lane == 0) flag[0] = (m >= 32) ? 0 : 1;
}

// ---------------------------------------------------------------- convert (elementwise)
__global__ __launch_bounds__(256) void convert_vec(
    const void* __restrict__ src, u16* __restrict__ dst, int n, const int* __restrict__ flag)
{
    int stride = gridDim.x * 256;
    int i0 = blockIdx.x * 256 + threadIdx.x;
    if (*flag) {
        const float* s = (const float*)src;
        for (int i = i0; i < n; i += stride) dst[i] = f2bf(s[i]);
    } else {
        const u16* s = (const u16*)src;
        for (int i = i0; i < n; i += stride) dst[i] = s[i];
    }
}

// ---------------------------------------------------------------- transpose+convert
__global__ __launch_bounds__(256) void transpose_cvt(
    const void* __restrict__ w0, const void* __restrict__ w1,
    const void* __restrict__ w2, const void* __restrict__ w3,
    u16* __restrict__ o0, u16* __restrict__ o1,
    u16* __restrict__ o2, u16* __restrict__ o3, const int* __restrict__ flag)
{
    const void* in; u16* out;
    switch (blockIdx.z) {
        case 0: in = w0; out = o0; break;
        case 1: in = w1; out = o1; break;
        case 2: in = w2; out = o2; break;
        default: in = w3; out = o3; break;
    }
    int n  = blockIdx.x * 64 + (threadIdx.x & 63);
    int kb = blockIdx.y * 32 + (threadIdx.x >> 6) * 8;
    u16 v[8];
    if (*flag) {
        const float* f = (const float*)in;
#pragma unroll
        for (int j = 0; j < 8; ++j) v[j] = f2bf(f[(size_t)(kb + j) * 1024 + n]);
    } else {
        const u16* s = (const u16*)in;
#pragma unroll
        for (int j = 0; j < 8; ++j) v[j] = s[(size_t)(kb + j) * 1024 + n];
    }
    uint4 pk;
    pk.x = (unsigned)v[0] | ((unsigned)v[1] << 16);
    pk.y = (unsigned)v[2] | ((unsigned)v[3] << 16);
    pk.z = (unsigned)v[4] | ((unsigned)v[5] << 16);
    pk.w = (unsigned)v[6] | ((unsigned)v[7] << 16);
    *(uint4*)(out + (size_t)n * 1024 + kb) = pk;
}

// ---------------------------------------------------------------- GEMM (m97-style)
__global__ __launch_bounds__(256) void gemm_bt(
    const u16* __restrict__ A, const u16* __restrict__ BT, void* __restrict__ C,
    int M, int Nn, int K, const int* __restrict__ flag, int fp32_out)
{
    __shared__ alignas(16) u16 As[128 * 32];
    __shared__ alignas(16) u16 Bs[128 * 32];
    const int tid  = threadIdx.x;
    const int lane = tid & 63;
    const int wv   = tid >> 6;
    const int wm   = wv >> 1, wn = wv & 1;
    const int bm   = blockIdx.x * 128, bn = blockIdx.y * 128;
    const int fr   = lane & 15, fk = lane >> 4;

    f32x4 acc[4][4];
#pragma unroll
    for (int i = 0; i < 4; ++i)
#pragma unroll
        for (int j = 0; j < 4; ++j) acc[i][j] = (f32x4){0.f, 0.f, 0.f, 0.f};

    for (int k0 = 0; k0 < K; k0 += 32) {
        __syncthreads();
#pragma unroll
        for (int p = 0; p < 2; ++p) {
            int i = tid + p * 256;
            int r = i >> 2, kc = (i & 3) << 3;
            gload_lds16(A  + (size_t)(bm + r) * K + k0 + kc,
                        (char*)As + (size_t)(wv * 64 + p * 256) * 16);
            gload_lds16(BT + (size_t)(bn + r) * K + k0 + kc,
                        (char*)Bs + (size_t)(wv * 64 + p * 256) * 16);
        }
        __syncthreads();
        bf16x8 af[4], bfr[4];
#pragma unroll
        for (int mi = 0; mi < 4; ++mi)
            af[mi] = *(const bf16x8*)(As + (wm * 64 + mi * 16 + fr) * 32 + fk * 8);
#pragma unroll
        for (int ni = 0; ni < 4; ++ni)
            bfr[ni] = *(const bf16x8*)(Bs + (wn * 64 + ni * 16 + fr) * 32 + fk * 8);
#pragma unroll
        for (int mi = 0; mi < 4; ++mi)
#pragma unroll
            for (int ni = 0; ni < 4; ++ni)
                acc[mi][ni] = MFMA16(af[mi], bfr[ni], acc[mi][ni], 0, 0, 0);
    }
    bool f32st = fp32_out && (*flag);
    if (f32st) {
        float* Cf = (float*)C;
#pragma unroll
        for (int mi = 0; mi < 4; ++mi)
#pragma unroll
            for (int ni = 0; ni < 4; ++ni)
#pragma unroll
                for (int j = 0; j < 4; ++j) {
                    int row = bm + wm * 64 + mi * 16 + fk * 4 + j;
                    int col = bn + wn * 64 + ni * 16 + fr;
                    Cf[(size_t)row * Nn + col] = acc[mi][ni][j];
                }
    } else {
        u16* Cb = (u16*)C;
#pragma unroll
        for (int mi = 0; mi < 4; ++mi)
#pragma unroll
            for (int ni = 0; ni < 4; ++ni)
#pragma unroll
                for (int j = 0; j < 4; ++j) {
                    int row = bm + wm * 64 + mi * 16 + fk * 4 + j;
                    int col = bn + wn * 64 + ni * 16 + fr;
                    Cb[(size_t)row * Nn + col] = f2bf(acc[mi][ni][j]);
                }
    }
}

// ---------------------------------------------------------------- fused QKV GEMM
// A [8192][1024], BT = [wqT;wkT;wvT] contiguous [3072][1024]; writes Q/K/V bufs.
__global__ __launch_bounds__(256) void gemm_qkv(
    const u16* __restrict__ A, const u16* __restrict__ BT,
    u16* __restrict__ Qo, u16* __restrict__ Ko, u16* __restrict__ Vo)
{
    __shared__ alignas(16) u16 As[128 * 32];
    __shared__ alignas(16) u16 Bs[128 * 32];
    const int tid  = threadIdx.x;
    const int lane = tid & 63;
    const int wv   = tid >> 6;
    const int wm   = wv >> 1, wn = wv & 1;
    const int bm   = blockIdx.x * 128, bn = blockIdx.y * 128;
    const int fr   = lane & 15, fk = lane >> 4;

    f32x4 acc[4][4];
#pragma unroll
    for (int i = 0; i < 4; ++i)
#pragma unroll
        for (int j = 0; j < 4; ++j) acc[i][j] = (f32x4){0.f, 0.f, 0.f, 0.f};

    for (int k0 = 0; k0 < 1024; k0 += 32) {
        __syncthreads();
#pragma unroll
        for (int p = 0; p < 2; ++p) {
            int i = tid + p * 256;
            int r = i >> 2, kc = (i & 3) << 3;
            gload_lds16(A  + (size_t)(bm + r) * 1024 + k0 + kc,
                        (char*)As + (size_t)(wv * 64 + p * 256) * 16);
            gload_lds16(BT + (size_t)(bn + r) * 1024 + k0 + kc,
                        (char*)Bs + (size_t)(wv * 64 + p * 256) * 16);
        }
        __syncthreads();
        bf16x8 af[4], bfr[4];
#pragma unroll
        for (int mi = 0; mi < 4; ++mi)
            af[mi] = *(const bf16x8*)(As + (wm * 64 + mi * 16 + fr) * 32 + fk * 8);
#pragma unroll
        for (int ni = 0; ni < 4; ++ni)
            bfr[ni] = *(const bf16x8*)(Bs + (wn * 64 + ni * 16 + fr) * 32 + fk * 8);
#pragma unroll
        for (int mi = 0; mi < 4; ++mi)
#pragma unroll
            for (int ni = 0; ni < 4; ++ni)
                acc[mi][ni] = MFMA16(af[mi], bfr[ni], acc[mi][ni], 0, 0, 0);
    }
    const int seg = bn >> 10;
    u16* Cb = (seg == 0) ? Qo : (seg == 1) ? Ko : Vo;
    const int cb = bn & 1023;
#pragma unroll
    for (int mi = 0; mi < 4; ++mi)
#pragma unroll
        for (int ni = 0; ni < 4; ++ni)
#pragma unroll
            for (int j = 0; j < 4; ++j) {
                int row = bm + wm * 64 + mi * 16 + fk * 4 + j;
                int col = cb + wn * 64 + ni * 16 + fr;
                Cb[(size_t)row * 1024 + col] = f2bf(acc[mi][ni][j]);
            }
}

// ---------------------------------------------------------------- beta = sigmoid(x @ Wbeta)
__global__ __launch_bounds__(256) void beta_kernel(
    const u16* __restrict__ x, const u16* __restrict__ Wb, float* __restrict__ beta)
{
    int row  = blockIdx.x * 4 + (threadIdx.x >> 6);
    int lane = threadIdx.x & 63;
    const u16* xr = x + (size_t)row * 1024;
    float a0 = 0.f, a1 = 0.f, a2 = 0.f, a3 = 0.f;
    for (int c = 0; c < 16; ++c) {
        int k = c * 64 + lane;
        float xv = bf2f(xr[k]);
        uint2 w = *(const uint2*)(Wb + (size_t)k * 4);
        a0 += xv * bf2f(w.x);
        a1 += xv * bf2f(w.x >> 16);
        a2 += xv * bf2f(w.y);
        a3 += xv * bf2f(w.y >> 16);
    }
#pragma unroll
    for (int m = 1; m < 64; m <<= 1) {
        a0 += __shfl_xor(a0, m); a1 += __shfl_xor(a1, m);
        a2 += __shfl_xor(a2, m); a3 += __shfl_xor(a3, m);
    }
    if (lane == 0) {
        int b = row >> 10, nn = row & 1023;
        beta[(size_t)(b * 4 + 0) * 1024 + nn] = 1.f / (1.f + expf(-a0));
        beta[(size_t)(b * 4 + 1) * 1024 + nn] = 1.f / (1.f + expf(-a1));
        beta[(size_t)(b * 4 + 2) * 1024 + nn] = 1.f / (1.f + expf(-a2));
        beta[(size_t)(b * 4 + 3) * 1024 + nn] = 1.f / (1.f + expf(-a3));
    }
}

// ---------------------------------------------------------------- per-head l2norm (in place)
__global__ __launch_bounds__(256) void l2norm_qk(u16* __restrict__ Q, u16* __restrict__ K)
{
    u16* base = blockIdx.y ? K : Q;
    int w    = blockIdx.x * 4 + (threadIdx.x >> 6);   // row*4 + h
    int lane = threadIdx.x & 63;
    u16* p = base + (size_t)(w >> 2) * 1024 + (w & 3) * 256 + lane * 4;
    uint2 u = *(const uint2*)p;
    float f0 = bf2f(u.x), f1 = bf2f(u.x >> 16), f2 = bf2f(u.y), f3 = bf2f(u.y >> 16);
    float ss = f0 * f0 + f1 * f1 + f2 * f2 + f3 * f3;
#pragma unroll
    for (int m = 1; m < 64; m <<= 1) ss += __shfl_xor(ss, m);
    float inv = rsqrtf(ss + 1e-20f);
    uint2 o;
    o.x = (unsigned)f2bf(f0 * inv) | ((unsigned)f2bf(f1 * inv) << 16);
    o.y = (unsigned)f2bf(f2 * inv) | ((unsigned)f2bf(f3 * inv) << 16);
    *(uint2*)p = o;
}

// ---------------------------------------------------------------- Phase A (chunked WY precompute)
#define AP 68
__global__ __launch_bounds__(256) void phaseA(
    const u16* __restrict__ Kb, const u16* __restrict__ Qb,
    const float* __restrict__ Bp,
    u16* __restrict__ Thi, u16* __restrict__ Tlo, u16* __restrict__ QKg,
    u16* __restrict__ KTg)
{
    const int bh = blockIdx.x >> 4, ch = blockIdx.x & 15;
    const int bq = bh >> 2, h = bh & 3;
    const int tid = threadIdx.x;
    const int w = tid >> 6, L = tid & 63, fr = L & 15, fk = L >> 4;

    __shared__ u16 Ks[64 * 264];
    __shared__ u16 Qs[64 * 264];
    __shared__ float Af[64 * AP];
    __shared__ float Tf[64 * AP];
    __shared__ float bc[64];

    const size_t crow = ((size_t)bq * 1024 + ch * 64) * 1024 + (size_t)h * 256;
#pragma unroll
    for (int i = 0; i < 8; ++i) {
        int row = i * 8 + (tid >> 5), c8 = (tid & 31) * 8;
        uint4 kv = *(const uint4*)(Kb + crow + (size_t)row * 1024 + c8);
        uint4 qv = *(const uint4*)(Qb + crow + (size_t)row * 1024 + c8);
        *(uint4*)(Ks + row * 264 + c8) = kv;
        *(uint4*)(Qs + row * 264 + c8) = qv;
    }
    if (tid < 64) bc[tid] = Bp[(size_t)bh * 1024 + ch * 64 + tid];
    __syncthreads();

    // K^T chunk -> global (coalesced; avoids phaseB LDS transpose)
    const size_t kbase = (size_t)(bh * 16 + ch) * 16384;
#pragma unroll
    for (int i = 0; i < 8; ++i) {
        int item = tid + i * 256;
        int t = item & 63, g = item >> 6;        // g: dk-group of 8
        union { uint4 q; u16 u[8]; } U;
        U.q = *(const uint4*)(Ks + t * 264 + g * 8);
#pragma unroll
        for (int e = 0; e < 8; ++e)
            KTg[kbase + (size_t)(g * 8 + e) * 64 + t] = U.u[e];
    }

    f32x4 kk[4], qk[4];
#pragma unroll
    for (int n = 0; n < 4; ++n) { kk[n] = (f32x4){0,0,0,0}; qk[n] = (f32x4){0,0,0,0}; }
#pragma unroll
    for (int k0 = 0; k0 < 8; ++k0) {
        bf16x8 ak = *(const bf16x8*)(Ks + (w * 16 + fr) * 264 + k0 * 32 + fk * 8);
        bf16x8 aq = *(const bf16x8*)(Qs + (w * 16 + fr) * 264 + k0 * 32 + fk * 8);
#pragma unroll
        for (int n = 0; n < 4; ++n) {
            bf16x8 bk = *(const bf16x8*)(Ks + (n * 16 + fr) * 264 + k0 * 32 + fk * 8);
            kk[n] = MFMA16(ak, bk, kk[n], 0, 0, 0);
            qk[n] = MFMA16(aq, bk, qk[n], 0, 0, 0);
        }
    }
    const size_t obase = (size_t)(bh * 16 + ch) * 4096;
#pragma unroll
    for (int n = 0; n < 4; ++n)
#pragma unroll
        for (int j = 0; j < 4; ++j) {
            int t = w * 16 + fk * 4 + j, s = n * 16 + fr;
            Af[t * AP + s] = (s < t) ? bc[t] * kk[n][j] : 0.f;
            QKg[obase + t * 64 + s] = f2bf((s <= t) ? qk[n][j] : 0.f);
        }
    __syncthreads();

    // forward substitution: T[t][:] = e_t - sum_{s<t} A[t][s] T[s][:]
    {
        int j = w * 16 + fr;   // column owned by this lane group
        int p = fk;            // partial index 0..3
        for (int t = 0; t < 64; ++t) {
            float acc = 0.f;
            for (int s = p; s < t; s += 4) acc += Af[t * AP + s] * Tf[s * AP + j];
            acc += __shfl_xor(acc, 16);
            acc += __shfl_xor(acc, 32);
            float val = ((t == j) ? 1.f : 0.f) - acc;
            if (p == 0) Tf[t * AP + j] = val;
        }
    }
    __syncthreads();
#pragma unroll
    for (int e = 0; e < 16; ++e) {
        int idx = tid + e * 256;
        int t = idx >> 6, s = idx & 63;
        float f = Tf[t * AP + s];
        u16 hh = f2bf(f);
        Thi[obase + idx] = hh;
        Tlo[obase + idx] = f2bf(f - bf2f(hh));
    }
}

// ---------------------------------------------------------------- Phase B (chunked WY scan)
// 512 blocks: bh = bid&31, dvb = bid>>5. Raw lgkm-only barriers (global loads
// stay in flight across them); all global reads prefetched into regs with
// issue-after-last-use so HBM latency hides under compute + barriers.
#define KTP 72
#define SHP 264
__global__ __launch_bounds__(256) void phaseB(
    const u16* __restrict__ Kb, const u16* __restrict__ Qb, u16* Vb,
    const float* __restrict__ Bp,
    const u16* __restrict__ Thi, const u16* __restrict__ Tlo,
    const u16* __restrict__ QKg, const u16* __restrict__ KTg)
{
    const int bh  = blockIdx.x & 31;
    const int dvb = blockIdx.x >> 5;      // 0..15
    const int bq = bh >> 2, h = bh & 3;
    const int tid = threadIdx.x;
    const int w = tid >> 6, L = tid & 63, fr = L & 15, fk = L >> 4;

    __shared__ u16 S_hi[16 * SHP];   // [dv][dk]
    __shared__ u16 S_lo[16 * SHP];
    __shared__ u16 W_T[16 * KTP];    // [dv][t]
    __shared__ u16 E_T[16 * KTP];
    __shared__ float bc[1024];

    for (int i = tid; i < 16 * SHP; i += 256) { S_hi[i] = 0; S_lo[i] = 0; }
    for (int i = tid; i < 1024; i += 256) bc[i] = Bp[(size_t)bh * 1024 + i];
    __syncthreads();

    const size_t rb = ((size_t)bq * 1024) * 1024 + (size_t)h * 256;

    bf16x8 th[2], tl[2], qk2[2], kf[2][4], kq[8], qq[8];
    u16 vr[4];

    auto pf_kqv = [&](int c) {
        const size_t crow = rb + (size_t)(c * 64) * 1024;
        const size_t arow = crow + (size_t)(w * 16 + fr) * 1024 + fk * 8;
#pragma unroll
        for (int k0 = 0; k0 < 8; ++k0) {
            kq[k0] = *(const bf16x8*)(Kb + arow + k0 * 32);
            qq[k0] = *(const bf16x8*)(Qb + arow + k0 * 32);
        }
#pragma unroll
        for (int j = 0; j < 4; ++j)
            vr[j] = Vb[crow + (size_t)(w * 16 + fk * 4 + j) * 1024 + dvb * 16 + fr];
    };
    auto pf_T = [&](int c) {
        const size_t tbase = (size_t)(bh * 16 + c) * 4096 + (size_t)(w * 16 + fr) * 64 + fk * 8;
#pragma unroll
        for (int k0 = 0; k0 < 2; ++k0) {
            th[k0] = *(const bf16x8*)(Thi + tbase + k0 * 32);
            tl[k0] = *(const bf16x8*)(Tlo + tbase + k0 * 32);
        }
    };
    auto pf_qk = [&](int c) {
        const size_t tbase = (size_t)(bh * 16 + c) * 4096 + (size_t)(w * 16 + fr) * 64 + fk * 8;
#pragma unroll
        for (int k0 = 0; k0 < 2; ++k0)
            qk2[k0] = *(const bf16x8*)(QKg + tbase + k0 * 32);
    };
    auto pf_kf = [&](int c) {
        const size_t kbase = (size_t)(bh * 16 + c) * 16384;
#pragma unroll
        for (int k0 = 0; k0 < 2; ++k0)
#pragma unroll
            for (int nn = 0; nn < 4; ++nn)
                kf[k0][nn] = *(const bf16x8*)(KTg + kbase
                              + (size_t)(w * 64 + nn * 16 + fr) * 64 + k0 * 32 + fk * 8);
    };

    pf_kqv(0); pf_T(0); pf_qk(0); pf_kf(0);

    for (int c = 0; c < 16; ++c) {
        const size_t crow = rb + (size_t)(c * 64) * 1024;
        // -------- (B) P = K@S0, O1 = Q@S0
        f32x4 accP = (f32x4){0,0,0,0}, accO = (f32x4){0,0,0,0};
#pragma unroll
        for (int k0 = 0; k0 < 8; ++k0) {
            bf16x8 shi = *(const bf16x8*)(S_hi + fr * SHP + k0 * 32 + fk * 8);
            bf16x8 slo = *(const bf16x8*)(S_lo + fr * SHP + k0 * 32 + fk * 8);
            accP = MFMA16(kq[k0], shi, accP, 0, 0, 0);
            accP = MFMA16(kq[k0], slo, accP, 0, 0, 0);
            accO = MFMA16(qq[k0], shi, accO, 0, 0, 0);
            accO = MFMA16(qq[k0], slo, accO, 0, 0, 0);
        }
        // -------- (C) W^T = beta*(V - P)
#pragma unroll
        for (int j = 0; j < 4; ++j) {
            int t = w * 16 + fk * 4 + j;
            W_T[fr * KTP + t] = f2bf(bc[c * 64 + t] * (bf2f(vr[j]) - accP[j]));
        }
        if (c + 1 < 16) pf_kqv(c + 1);   // kq/qq/vr dead -> refill, stays in flight
        BARS();
        // -------- (D) E = T @ W
        f32x4 accE = (f32x4){0,0,0,0};
#pragma unroll
        for (int k0 = 0; k0 < 2; ++k0) {
            bf16x8 wf = *(const bf16x8*)(W_T + fr * KTP + k0 * 32 + fk * 8);
            accE = MFMA16(th[k0], wf, accE, 0, 0, 0);
            accE = MFMA16(tl[k0], wf, accE, 0, 0, 0);
        }
#pragma unroll
        for (int j = 0; j < 4; ++j)
            E_T[fr * KTP + (w * 16 + fk * 4 + j)] = f2bf(accE[j]);
        if (c + 1 < 16) pf_T(c + 1);     // th/tl dead -> refill
        BARS();
        // -------- (E) O = O1 + QKt @ E -> Vb
        bf16x8 ef[2];
#pragma unroll
        for (int k0 = 0; k0 < 2; ++k0) {
            ef[k0] = *(const bf16x8*)(E_T + fr * KTP + k0 * 32 + fk * 8);
            accO = MFMA16(qk2[k0], ef[k0], accO, 0, 0, 0);
        }
#pragma unroll
        for (int j = 0; j < 4; ++j)
            Vb[crow + (size_t)(w * 16 + fk * 4 + j) * 1024 + dvb * 16 + fr] = f2bf(accO[j]);
        if (c + 1 < 16) pf_qk(c + 1);    // qk2 dead -> refill
        // -------- (F) S += E^T @ K
        f32x4 dS[4];
#pragma unroll
        for (int nn = 0; nn < 4; ++nn) dS[nn] = (f32x4){0,0,0,0};
#pragma unroll
        for (int k0 = 0; k0 < 2; ++k0)
#pragma unroll
            for (int nn = 0; nn < 4; ++nn)
                dS[nn] = MFMA16(ef[k0], kf[k0][nn], dS[nn], 0, 0, 0);
        if (c + 1 < 16) pf_kf(c + 1);    // kf dead -> refill
#pragma unroll
        for (int nn = 0; nn < 4; ++nn)
#pragma unroll
            for (int j = 0; j < 4; ++j) {
                int idx = (fk * 4 + j) * SHP + (w * 64 + nn * 16 + fr);
                float s = bf2f(S_hi[idx]) + bf2f(S_lo[idx]) + dS[nn][j];
                u16 hh = f2bf(s);
                S_hi[idx] = hh;
                S_lo[idx] = f2bf(s - bf2f(hh));
            }
        BARS();
    }
}

// ---------------------------------------------------------------- RMSNorm over Dv, in place
__global__ __launch_bounds__(256) void rmsnorm_o(u16* V, const u16* __restrict__ gn)
{
    int w    = blockIdx.x * 4 + (threadIdx.x >> 6);   // (b*1024+t)*4 + h
    int lane = threadIdx.x & 63;
    u16* p = V + (size_t)(w >> 2) * 1024 + (w & 3) * 256 + lane * 4;
    uint2 u = *(const uint2*)p;
    float f0 = bf2f(u.x), f1 = bf2f(u.x >> 16), f2 = bf2f(u.y), f3 = bf2f(u.y >> 16);
    float ss = f0 * f0 + f1 * f1 + f2 * f2 + f3 * f3;
#pragma unroll
    for (int m = 1; m < 64; m <<= 1) ss += __shfl_xor(ss, m);
    float sc = rsqrtf(ss * (1.0f / 256.0f) + 1e-5f);
    int d0 = lane * 4;
    uint2 gu = *(const uint2*)(gn + d0);
    float g0 = bf2f(gu.x), g1 = bf2f(gu.x >> 16), g2 = bf2f(gu.y), g3 = bf2f(gu.y >> 16);
    uint2 o;
    o.x = (unsigned)f2bf(f0 * sc * g0) | ((unsigned)f2bf(f1 * sc * g1) << 16);
    o.y = (unsigned)f2bf(f2 * sc * g2) | ((unsigned)f2bf(f3 * sc * g3) << 16);
    *(uint2*)p = o;
}

// ---------------------------------------------------------------- launch
extern "C" void kernel_launch(void* const* d_in, const int* in_sizes, int n_in,
                              void* d_out, int out_size, void* d_ws, size_t ws_size,
                              hipStream_t stream)
{
    const void* x  = d_in[0];
    const void* Wq = d_in[1];
    const void* Wk = d_in[2];
    const void* Wv = d_in[3];
    const void* Wb = d_in[4];
    const void* Wo = d_in[5];
    const void* gn = d_in[6];

    char* ws = (char*)d_ws;
    const size_t OFF_FLAG = 0;                        // 4 KB block
    const size_t OFF_WBC  = 4096;                     // 8 KB (Wbeta bf16)
    const size_t OFF_GNC  = OFF_WBC + 8192;           // 4 KB (g_norm bf16)
    const size_t OFF_XB   = OFF_GNC + 4096;           // 16 MB (x bf16; reused by T/QKt)
    const size_t OFF_WQT  = OFF_XB + 16777216;        // 2 MB  (wqT/wkT/wvT contiguous!)
    const size_t OFF_WKT  = OFF_WQT + 2097152;        // 2 MB
    const size_t OFF_WVT  = OFF_WKT + 2097152;        // 2 MB
    const size_t OFF_WOT  = OFF_WVT + 2097152;        // 2 MB
    const size_t OFF_Q    = OFF_WOT + 2097152;        // 16 MB
    const size_t OFF_K    = OFF_Q + 16777216;         // 16 MB
    const size_t OFF_V    = OFF_K + 16777216;         // 16 MB
    const size_t OFF_BP   = OFF_V + 16777216;         // 128 KB  -> ~72.6 MB total

    const size_t OFF_THI  = OFF_XB;                   // overlay in dead Xb
    const size_t OFF_TLO  = OFF_XB + 4194304;
    const size_t OFF_QKT  = OFF_XB + 8388608;

    int*   flag = (int*)(ws + OFF_FLAG);
    u16*   Wbc  = (u16*)(ws + OFF_WBC);
    u16*   gnc  = (u16*)(ws + OFF_GNC);
    u16*   Xb   = (u16*)(ws + OFF_XB);
    u16*   wqT  = (u16*)(ws + OFF_WQT);
    u16*   wkT  = (u16*)(ws + OFF_WKT);
    u16*   wvT  = (u16*)(ws + OFF_WVT);
    u16*   woT  = (u16*)(ws + OFF_WOT);
    u16*   Qb   = (u16*)(ws + OFF_Q);
    u16*   Kb   = (u16*)(ws + OFF_K);
    u16*   Vb   = (u16*)(ws + OFF_V);
    float* Bp   = (float*)(ws + OFF_BP);
    u16*   Thi  = (u16*)(ws + OFF_THI);
    u16*   Tlo  = (u16*)(ws + OFF_TLO);
    u16*   QKg  = (u16*)(ws + OFF_QKT);
    u16*   KTg  = (u16*)d_out;   // dead until final GEMM overwrites it

    detect_dtype<<<1, 64, 0, stream>>>((const unsigned*)Wq, flag);
    convert_vec<<<2048, 256, 0, stream>>>(x, Xb, 8388608, flag);
    convert_vec<<<16, 256, 0, stream>>>(Wb, Wbc, 4096, flag);
    convert_vec<<<1, 256, 0, stream>>>(gn, gnc, 256, flag);
    transpose_cvt<<<dim3(16, 32, 4), 256, 0, stream>>>(Wq, Wk, Wv, Wo, wqT, wkT, wvT, woT, flag);

    gemm_qkv<<<dim3(64, 24), 256, 0, stream>>>(Xb, wqT, Qb, Kb, Vb);
    beta_kernel<<<2048, 256, 0, stream>>>(Xb, Wbc, Bp);
    l2norm_qk<<<dim3(8192, 2), 256, 0, stream>>>(Qb, Kb);

    phaseA<<<512, 256, 0, stream>>>(Kb, Qb, Bp, Thi, Tlo, QKg, KTg);
    phaseB<<<512, 256, 0, stream>>>(Kb, Qb, Vb, Bp, Thi, Tlo, QKg, KTg);

    rmsnorm_o<<<8192, 256, 0, stream>>>(Vb, gnc);
    gemm_bt<<<dim3(64, 8), 256, 0, stream>>>(Vb, woT, d_out, 8192, 1024, 1024, flag, 1);
}